// Round 5
// baseline (494.742 us; speedup 1.0000x reference)
//
#include <hip/hip_runtime.h>

// MoE: T=8192, D=1024, E=8, top-2, H=2730 (pad 2752), capacity=1024.
// Pipeline: memset(out) -> router (atomic-free) -> rank_select -> gather(bf16)
//   -> convert_all (fp32->bf16, one kernel) -> gemm1 (swiglu, dbuf prefetch)
//   -> gemm2 (down, dbuf prefetch). GEMMs: gload_lds + both-sides XOR swizzle +
//   double-buffered LDS with next-tile prefetch issued before current compute.

typedef float  f4  __attribute__((ext_vector_type(4)));
typedef float  f2  __attribute__((ext_vector_type(2)));
typedef __bf16 bf8v __attribute__((ext_vector_type(8)));
typedef __bf16 bf4v __attribute__((ext_vector_type(4)));
typedef unsigned int u32;
typedef unsigned long long u64;
typedef u32 u4v __attribute__((ext_vector_type(4)));

#define NTOK 8192
#define DM   1024
#define NE   8
#define HD   2730
#define HP   2752
#define CAP  1024

__device__ __forceinline__ f4 mfma_bf16(bf8v a, bf8v b, f4 c) {
  return __builtin_amdgcn_mfma_f32_16x16x32_bf16(a, b, c, 0, 0, 0);
}

__device__ __forceinline__ void gl_lds16(const void* g, void* l) {
  __builtin_amdgcn_global_load_lds(
      (const __attribute__((address_space(1))) unsigned int*)g,
      (__attribute__((address_space(3))) unsigned int*)l, 16, 0, 0);
}

// ---------------- router: logits + top-2 + softmax -> dense u64 records (no atomics) ----------------
// rec = (p_bits << 32) | (0xFFFFFFFF - (flat_pos*8 | expert)); u64 '>' == (p desc, pos asc).
__global__ __launch_bounds__(256) void router_kernel(
    const float* __restrict__ x, const float* __restrict__ gw, u64* __restrict__ recs) {
  __shared__ float gws[NE][DM];
  int tid = threadIdx.x;
  for (int i = tid * 4; i < NE * DM; i += 1024)
    *reinterpret_cast<f4*>(&gws[0][i]) = *reinterpret_cast<const f4*>(gw + i);
  __syncthreads();
  int lane = tid & 63, wave = tid >> 6;
  int tbase = blockIdx.x * 16 + wave * 4;
#pragma unroll
  for (int tt = 0; tt < 4; ++tt) {
    int t = tbase + tt;
    const f4* xr = reinterpret_cast<const f4*>(x + (size_t)t * DM);
    float acc[NE];
#pragma unroll
    for (int e = 0; e < NE; ++e) acc[e] = 0.f;
#pragma unroll
    for (int i = 0; i < 4; ++i) {
      f4 xv = xr[i * 64 + lane];
#pragma unroll
      for (int e = 0; e < NE; ++e) {
        f4 gv = *reinterpret_cast<const f4*>(&gws[e][i * 256 + lane * 4]);
        acc[e] += xv[0] * gv[0] + xv[1] * gv[1] + xv[2] * gv[2] + xv[3] * gv[3];
      }
    }
#pragma unroll
    for (int e = 0; e < NE; ++e) {
      float v = acc[e];
#pragma unroll
      for (int off = 32; off > 0; off >>= 1) v += __shfl_xor(v, off);
      acc[e] = v;
    }
    if (lane == 0) {
      float l0 = -1e30f, l1 = -1e30f; int i0 = 0, i1 = 0;
#pragma unroll
      for (int e = 0; e < NE; ++e) {
        float v = acc[e];
        if (v > l0)      { l1 = l0; i1 = i0; l0 = v; i0 = e; }
        else if (v > l1) { l1 = v; i1 = e; }
      }
      float e1 = expf(l1 - l0);
      float s  = 1.f + e1;
      float p0 = 1.f / s, p1 = e1 / s;
      float s2 = p0 + p1;
      p0 /= s2; p1 /= s2;
      u32 pf0 = 0xFFFFFFFFu - (((u32)(2 * t)     << 3) | (u32)i0);
      u32 pf1 = 0xFFFFFFFFu - (((u32)(2 * t + 1) << 3) | (u32)i1);
      recs[2 * t]     = ((u64)__float_as_uint(p0) << 32) | pf0;
      recs[2 * t + 1] = ((u64)__float_as_uint(p1) << 32) | pf1;
    }
  }
}

// ---------------- rank_select: per-expert append (wave-aggregated LDS atomic) + count-rank ----------------
__global__ __launch_bounds__(1024) void rank_select(
    const u64* __restrict__ recs, int* __restrict__ etok, float* __restrict__ ep,
    int* __restrict__ ecnt) {
  __shared__ u64 keys[8192];   // n <= 8192 structurally
  __shared__ int lcnt;
  int e = blockIdx.x;
  int tid = threadIdx.x;
  int lane = tid & 63;
  if (tid == 0) lcnt = 0;
  __syncthreads();
  for (int s = tid; s < 2 * NTOK; s += 1024) {
    u64 r = recs[s];
    bool m = ((0xFFFFFFFFu - (u32)r) & 7u) == (u32)e;
    u64 mask = __ballot(m);
    int base = 0;
    if (lane == 0 && mask) base = atomicAdd(&lcnt, __popcll(mask));
    base = __shfl(base, 0);
    if (m) {
      int off = __popcll(mask & ((1ull << lane) - 1ull));
      keys[base + off] = r;
    }
  }
  __syncthreads();
  int n = lcnt;
  for (int i = tid; i < n; i += 1024) {
    u64 ki = keys[i];
    int r = 0;
#pragma unroll 8
    for (int j = 0; j < n; ++j) r += (keys[j] > ki);
    if (r < CAP) {
      u32 v = 0xFFFFFFFFu - (u32)ki;
      etok[e * CAP + r] = (int)(v >> 3);
      ep[e * CAP + r]   = __uint_as_float((u32)(ki >> 32));
    }
  }
  if (tid == 0) ecnt[e] = n < CAP ? n : CAP;
}

// ---------------- gather kept tokens -> bf16 ----------------
__global__ __launch_bounds__(256) void gather_kernel(
    const float* __restrict__ x, const int* __restrict__ etok, const int* __restrict__ ecnt,
    __bf16* __restrict__ Xe) {
  int e = blockIdx.x >> 10;
  int r = blockIdx.x & 1023;
  __bf16* dst = Xe + ((size_t)(e * CAP + r)) * DM;
  int tid = threadIdx.x;
  bf4v o;
  if (r < ecnt[e]) {
    int tok = etok[e * CAP + r] >> 1;
    f4 v = reinterpret_cast<const f4*>(x + (size_t)tok * DM)[tid];
    o[0] = (__bf16)v[0]; o[1] = (__bf16)v[1]; o[2] = (__bf16)v[2]; o[3] = (__bf16)v[3];
  } else {
    o[0] = (__bf16)0.f; o[1] = (__bf16)0.f; o[2] = (__bf16)0.f; o[3] = (__bf16)0.f;
  }
  reinterpret_cast<bf4v*>(dst)[tid] = o;
}

// ---------------- weight conversion fp32 -> bf16, all three in one launch ----------------
// z=0: wgate [NE][HD][DM] -> [NE][HP][DM]; z=1: wup same; z=2: wdown [NE][DM][HD] -> [NE][DM][HP].
__global__ __launch_bounds__(256) void convert_all(
    const float* __restrict__ wg, const float* __restrict__ wu, const float* __restrict__ wd,
    __bf16* __restrict__ wgb, __bf16* __restrict__ wub, __bf16* __restrict__ wdb) {
  int e = blockIdx.y;
  int z = blockIdx.z;
  int idx = blockIdx.x * 256 + threadIdx.x;
  bf8v o;
  if (z < 2) {
    const float* src = z ? wu : wg;
    __bf16* dst = z ? wub : wgb;
    int row = idx >> 7;
    int c = (idx & 127) << 3;
    if (row < HD) {
      const float* s = src + ((size_t)e * HD + row) * DM + c;
      f4 a = *reinterpret_cast<const f4*>(s);
      f4 b = *reinterpret_cast<const f4*>(s + 4);
#pragma unroll
      for (int q = 0; q < 4; ++q) { o[q] = (__bf16)a[q]; o[q + 4] = (__bf16)b[q]; }
    } else {
#pragma unroll
      for (int q = 0; q < 8; ++q) o[q] = (__bf16)0.f;
    }
    *reinterpret_cast<bf8v*>(dst + ((size_t)e * HP + row) * DM + c) = o;
  } else {
    int row = idx / 344;
    int c = (idx % 344) << 3;
    const float* s = wd + ((size_t)e * DM + row) * HD + c;
    if (c + 8 <= HD) {
      f2 q0 = *reinterpret_cast<const f2*>(s);
      f2 q1 = *reinterpret_cast<const f2*>(s + 2);
      f2 q2 = *reinterpret_cast<const f2*>(s + 4);
      f2 q3 = *reinterpret_cast<const f2*>(s + 6);
      o[0] = (__bf16)q0[0]; o[1] = (__bf16)q0[1]; o[2] = (__bf16)q1[0]; o[3] = (__bf16)q1[1];
      o[4] = (__bf16)q2[0]; o[5] = (__bf16)q2[1]; o[6] = (__bf16)q3[0]; o[7] = (__bf16)q3[1];
    } else {
#pragma unroll
      for (int q = 0; q < 8; ++q) o[q] = (c + q < HD) ? (__bf16)s[q] : (__bf16)0.f;
    }
    *reinterpret_cast<bf8v*>(wdb + ((size_t)e * DM + row) * HP + c) = o;
  }
}

// ============ bf16 GEMMs: gload_lds + XOR swizzle + double-buffered prefetch ============
// T3-minimal schedule: STAGE(0); for kt { barrier(=vmcnt drain of stage kt);
//   STAGE(kt+1); ds_read+MFMA on buf kt }. Next-tile HBM latency hides under MFMA.

__global__ __launch_bounds__(256) void gemm1_swiglu_bf(
    const __bf16* __restrict__ Xe, const __bf16* __restrict__ wgb, const __bf16* __restrict__ wub,
    const int* __restrict__ ecnt, __bf16* __restrict__ Hbuf) {
  int bid = blockIdx.x;                         // 2752 = 8 XCD * 344
  int wgid = (bid & 7) * 344 + (bid >> 3);      // each XCD owns one expert
  int pm = wgid & 7;
  int pn = (wgid >> 3) % 43;
  int e  = wgid / 344;
  int ne = ecnt[e];
  int m0 = pm * 128, n0 = pn * 64;
  if (m0 >= ne) return;

  __shared__ __align__(16) __bf16 As[2][128 * 64];   // 32 KB
  __shared__ __align__(16) __bf16 Bgs[2][64 * 64];   // 16 KB
  __shared__ __align__(16) __bf16 Bus[2][64 * 64];   // 16 KB

  int tid = threadIdx.x;
  int lane = tid & 63, wave = tid >> 6;
  int wm = wave >> 1, wn = wave & 1;
  int lr = lane >> 3;
  int scol = (((lane & 7) << 4) ^ (lr << 4)) >> 1;   // pre-swizzled src col (elems)

  f4 accG[4][2], accU[4][2];
#pragma unroll
  for (int m = 0; m < 4; ++m)
#pragma unroll
    for (int n = 0; n < 2; ++n) { accG[m][n] = (f4){0,0,0,0}; accU[m][n] = (f4){0,0,0,0}; }

  const __bf16* Ab = Xe + ((size_t)(e * CAP + m0)) * DM;
  const __bf16* Gb = wgb + (size_t)e * HP * DM + (size_t)n0 * DM;
  const __bf16* Ub = wub + (size_t)e * HP * DM + (size_t)n0 * DM;

  auto STAGE = [&](int buf, int kt) {
    int k0 = kt * 64;
#pragma unroll
    for (int i = 0; i < 4; ++i) {
      int rb = i * 32 + wave * 8 + lr;
      gl_lds16(Ab + (size_t)rb * DM + k0 + scol, (char*)As[buf] + i * 4096 + wave * 1024);
    }
#pragma unroll
    for (int i = 0; i < 2; ++i) {
      int rb = i * 32 + wave * 8 + lr;
      gl_lds16(Gb + (size_t)rb * DM + k0 + scol, (char*)Bgs[buf] + i * 4096 + wave * 1024);
      gl_lds16(Ub + (size_t)rb * DM + k0 + scol, (char*)Bus[buf] + i * 4096 + wave * 1024);
    }
  };

  STAGE(0, 0);
  for (int kt = 0; kt < 16; ++kt) {
    int cur = kt & 1;
    __syncthreads();                       // vmcnt(0) drain of STAGE(kt) + WAR fence
    if (kt + 1 < 16) STAGE(cur ^ 1, kt + 1);
    const char* Ac = (const char*)As[cur];
    const char* Gc = (const char*)Bgs[cur];
    const char* Uc = (const char*)Bus[cur];
#pragma unroll
    for (int kk = 0; kk < 2; ++kk) {
      int kb = kk * 64 + ((lane >> 4) << 4);
      bf8v af[4];
#pragma unroll
      for (int m = 0; m < 4; ++m) {
        int row = wm * 64 + m * 16 + (lane & 15);
        af[m] = *reinterpret_cast<const bf8v*>(Ac + ((row * 128 + kb) ^ ((row & 7) << 4)));
      }
      bf8v bg[2], bu[2];
#pragma unroll
      for (int n = 0; n < 2; ++n) {
        int row = wn * 32 + n * 16 + (lane & 15);
        int off = (row * 128 + kb) ^ ((row & 7) << 4);
        bg[n] = *reinterpret_cast<const bf8v*>(Gc + off);
        bu[n] = *reinterpret_cast<const bf8v*>(Uc + off);
      }
#pragma unroll
      for (int m = 0; m < 4; ++m)
#pragma unroll
        for (int n = 0; n < 2; ++n) {
          accG[m][n] = mfma_bf16(af[m], bg[n], accG[m][n]);
          accU[m][n] = mfma_bf16(af[m], bu[n], accU[m][n]);
        }
    }
  }

  __bf16* hb = Hbuf + (size_t)e * CAP * HP;
#pragma unroll
  for (int m = 0; m < 4; ++m)
#pragma unroll
    for (int n = 0; n < 2; ++n)
#pragma unroll
      for (int j = 0; j < 4; ++j) {
        int row = m0 + wm * 64 + m * 16 + ((lane >> 4) << 2) + j;
        int col = n0 + wn * 32 + n * 16 + (lane & 15);
        float g = accG[m][n][j];
        float u = accU[m][n][j];
        float h = g / (1.f + expf(-g)) * u;
        hb[(size_t)row * HP + col] = (__bf16)h;
      }
}

__global__ __launch_bounds__(256) void gemm2_down_bf(
    const __bf16* __restrict__ Hbuf, const __bf16* __restrict__ wdb,
    const int* __restrict__ ecnt, const int* __restrict__ etok, const float* __restrict__ ep,
    float* __restrict__ out) {
  int bid = blockIdx.x;                        // 1024 = 8 XCD * 128
  int wgid = (bid & 7) * 128 + (bid >> 3);
  int pm = wgid & 7;
  int pn = (wgid >> 3) & 15;
  int e  = wgid >> 7;
  int ne = ecnt[e];
  int m0 = pm * 128, n0 = pn * 64;
  if (m0 >= ne) return;

  __shared__ __align__(16) __bf16 As[2][128 * 64];   // 32 KB
  __shared__ __align__(16) __bf16 Bs[2][64 * 64];    // 16 KB

  int tid = threadIdx.x;
  int lane = tid & 63, wave = tid >> 6;
  int wm = wave >> 1, wn = wave & 1;
  int lr = lane >> 3;
  int scol = (((lane & 7) << 4) ^ (lr << 4)) >> 1;

  f4 acc[4][2];
#pragma unroll
  for (int m = 0; m < 4; ++m)
#pragma unroll
    for (int n = 0; n < 2; ++n) acc[m][n] = (f4){0,0,0,0};

  const __bf16* Ab = Hbuf + (size_t)(e * CAP + m0) * HP;
  const __bf16* Bb = wdb + (size_t)e * DM * HP + (size_t)n0 * HP;

  auto STAGE = [&](int buf, int kt) {
    int k0 = kt * 64;
#pragma unroll
    for (int i = 0; i < 4; ++i) {
      int rb = i * 32 + wave * 8 + lr;
      gl_lds16(Ab + (size_t)rb * HP + k0 + scol, (char*)As[buf] + i * 4096 + wave * 1024);
    }
#pragma unroll
    for (int i = 0; i < 2; ++i) {
      int rb = i * 32 + wave * 8 + lr;
      gl_lds16(Bb + (size_t)rb * HP + k0 + scol, (char*)Bs[buf] + i * 4096 + wave * 1024);
    }
  };

  STAGE(0, 0);
  for (int kt = 0; kt < HP / 64; ++kt) {       // 43 steps
    int cur = kt & 1;
    __syncthreads();
    if (kt + 1 < HP / 64) STAGE(cur ^ 1, kt + 1);
    const char* Ac = (const char*)As[cur];
    const char* Bc = (const char*)Bs[cur];
#pragma unroll
    for (int kk = 0; kk < 2; ++kk) {
      int kb = kk * 64 + ((lane >> 4) << 4);
      bf8v af[4];
#pragma unroll
      for (int m = 0; m < 4; ++m) {
        int row = wm * 64 + m * 16 + (lane & 15);
        af[m] = *reinterpret_cast<const bf8v*>(Ac + ((row * 128 + kb) ^ ((row & 7) << 4)));
      }
      bf8v bfr[2];
#pragma unroll
      for (int n = 0; n < 2; ++n) {
        int row = wn * 32 + n * 16 + (lane & 15);
        bfr[n] = *reinterpret_cast<const bf8v*>(Bc + ((row * 128 + kb) ^ ((row & 7) << 4)));
      }
#pragma unroll
      for (int m = 0; m < 4; ++m)
#pragma unroll
        for (int n = 0; n < 2; ++n)
          acc[m][n] = mfma_bf16(af[m], bfr[n], acc[m][n]);
    }
  }

#pragma unroll
  for (int m = 0; m < 4; ++m)
#pragma unroll
    for (int j = 0; j < 4; ++j) {
      int row = m0 + wm * 64 + m * 16 + ((lane >> 4) << 2) + j;
      if (row < ne) {
        float p  = ep[e * CAP + row];
        int tok  = etok[e * CAP + row] >> 1;
        float* orow = out + (size_t)tok * DM;
#pragma unroll
        for (int n = 0; n < 2; ++n) {
          int col = n0 + wn * 32 + n * 16 + (lane & 15);
          atomicAdd(orow + col, acc[m][n][j] * p);   // <=2 adds/elem, deterministic
        }
      }
    }
}

// ---------------- launch ----------------
extern "C" void kernel_launch(void* const* d_in, const int* in_sizes, int n_in,
                              void* d_out, int out_size, void* d_ws, size_t ws_size,
                              hipStream_t stream) {
  const float* x     = (const float*)d_in[0];
  const float* gw    = (const float*)d_in[1];
  const float* wgate = (const float*)d_in[2];
  const float* wup   = (const float*)d_in[3];
  const float* wdown = (const float*)d_in[4];
  float* out = (float*)d_out;
  char* ws = (char*)d_ws;

  u64*   recs = (u64*)  (ws + 0);           // 131072
  int*   etok = (int*)  (ws + 131072);      // 32768
  float* ep   = (float*)(ws + 163840);      // 32768
  int*   ecnt = (int*)  (ws + 196608);      // 256
  __bf16* Xe  = (__bf16*)(ws + 196864);     // 16777216 -> 16974080
  __bf16* Hbuf= (__bf16*)(ws + 16974080);   // 45088768 -> 62062848
  __bf16* wgb = (__bf16*)(ws + 62062848);   // 45088768 -> 107151616
  __bf16* wub = (__bf16*)(ws + 107151616);  // 45088768 -> 152240384
  __bf16* wdb = (__bf16*)(ws + 152240384);  // 45088768 -> 197329152

  hipMemsetAsync(out, 0, (size_t)NTOK * DM * sizeof(float), stream);
  router_kernel<<<NTOK / 16, 256, 0, stream>>>(x, gw, recs);
  rank_select<<<NE, 1024, 0, stream>>>(recs, etok, ep, ecnt);
  gather_kernel<<<NE * CAP, 256, 0, stream>>>(x, etok, ecnt, Xe);

  dim3 gcv(1376, NE, 3);
  convert_all<<<gcv, 256, 0, stream>>>(wgate, wup, wdown, wgb, wub, wdb);
  gemm1_swiglu_bf<<<8 * 43 * 8, 256, 0, stream>>>(Xe, wgb, wub, ecnt, Hbuf);
  gemm2_down_bf<<<8 * 16 * 8, 256, 0, stream>>>(Hbuf, wdb, ecnt, etok, ep, out);
}

// Round 6
// 478.412 us; speedup vs baseline: 1.0341x; 1.0341x over previous
//
#include <hip/hip_runtime.h>

// MoE: T=8192, D=1024, E=8, top-2, H=2730 (pad 2752), capacity=1024.
// Pipeline: memset(out) -> router (atomic-free) -> rank_select -> gather(bf16)
//   -> convert_all (fp32->bf16) -> gemm1 (swiglu, 128x128 tile, 2-barrier)
//   -> gemm2 (down, 128x128 tile, 2-barrier).
// GEMMs: gload_lds + both-sides XOR swizzle, single-buffered LDS (R4-proven
// structure; explicit dbuf measured -20% in R5 due to occupancy loss).

typedef float  f4  __attribute__((ext_vector_type(4)));
typedef float  f2  __attribute__((ext_vector_type(2)));
typedef __bf16 bf8v __attribute__((ext_vector_type(8)));
typedef __bf16 bf4v __attribute__((ext_vector_type(4)));
typedef unsigned int u32;
typedef unsigned long long u64;
typedef u32 u4v __attribute__((ext_vector_type(4)));

#define NTOK 8192
#define DM   1024
#define NE   8
#define HD   2730
#define HP   2752
#define CAP  1024

__device__ __forceinline__ f4 mfma_bf16(bf8v a, bf8v b, f4 c) {
  return __builtin_amdgcn_mfma_f32_16x16x32_bf16(a, b, c, 0, 0, 0);
}

__device__ __forceinline__ void gl_lds16(const void* g, void* l) {
  __builtin_amdgcn_global_load_lds(
      (const __attribute__((address_space(1))) unsigned int*)g,
      (__attribute__((address_space(3))) unsigned int*)l, 16, 0, 0);
}

// ---------------- router: logits + top-2 + softmax -> dense u64 records (no atomics) ----------------
// rec = (p_bits << 32) | (0xFFFFFFFF - (flat_pos*8 | expert)); u64 '>' == (p desc, pos asc).
__global__ __launch_bounds__(256) void router_kernel(
    const float* __restrict__ x, const float* __restrict__ gw, u64* __restrict__ recs) {
  __shared__ float gws[NE][DM];
  int tid = threadIdx.x;
  for (int i = tid * 4; i < NE * DM; i += 1024)
    *reinterpret_cast<f4*>(&gws[0][i]) = *reinterpret_cast<const f4*>(gw + i);
  __syncthreads();
  int lane = tid & 63, wave = tid >> 6;
  int tbase = blockIdx.x * 16 + wave * 4;
#pragma unroll
  for (int tt = 0; tt < 4; ++tt) {
    int t = tbase + tt;
    const f4* xr = reinterpret_cast<const f4*>(x + (size_t)t * DM);
    float acc[NE];
#pragma unroll
    for (int e = 0; e < NE; ++e) acc[e] = 0.f;
#pragma unroll
    for (int i = 0; i < 4; ++i) {
      f4 xv = xr[i * 64 + lane];
#pragma unroll
      for (int e = 0; e < NE; ++e) {
        f4 gv = *reinterpret_cast<const f4*>(&gws[e][i * 256 + lane * 4]);
        acc[e] += xv[0] * gv[0] + xv[1] * gv[1] + xv[2] * gv[2] + xv[3] * gv[3];
      }
    }
#pragma unroll
    for (int e = 0; e < NE; ++e) {
      float v = acc[e];
#pragma unroll
      for (int off = 32; off > 0; off >>= 1) v += __shfl_xor(v, off);
      acc[e] = v;
    }
    if (lane == 0) {
      float l0 = -1e30f, l1 = -1e30f; int i0 = 0, i1 = 0;
#pragma unroll
      for (int e = 0; e < NE; ++e) {
        float v = acc[e];
        if (v > l0)      { l1 = l0; i1 = i0; l0 = v; i0 = e; }
        else if (v > l1) { l1 = v; i1 = e; }
      }
      float e1 = expf(l1 - l0);
      float s  = 1.f + e1;
      float p0 = 1.f / s, p1 = e1 / s;
      float s2 = p0 + p1;
      p0 /= s2; p1 /= s2;
      u32 pf0 = 0xFFFFFFFFu - (((u32)(2 * t)     << 3) | (u32)i0);
      u32 pf1 = 0xFFFFFFFFu - (((u32)(2 * t + 1) << 3) | (u32)i1);
      recs[2 * t]     = ((u64)__float_as_uint(p0) << 32) | pf0;
      recs[2 * t + 1] = ((u64)__float_as_uint(p1) << 32) | pf1;
    }
  }
}

// ---------------- rank_select: per-expert append (wave-aggregated LDS atomic) + count-rank ----------------
__global__ __launch_bounds__(1024) void rank_select(
    const u64* __restrict__ recs, int* __restrict__ etok, float* __restrict__ ep,
    int* __restrict__ ecnt) {
  __shared__ u64 keys[8192];   // n <= 8192 structurally
  __shared__ int lcnt;
  int e = blockIdx.x;
  int tid = threadIdx.x;
  int lane = tid & 63;
  if (tid == 0) lcnt = 0;
  __syncthreads();
  for (int s = tid; s < 2 * NTOK; s += 1024) {
    u64 r = recs[s];
    bool m = ((0xFFFFFFFFu - (u32)r) & 7u) == (u32)e;
    u64 mask = __ballot(m);
    int base = 0;
    if (lane == 0 && mask) base = atomicAdd(&lcnt, __popcll(mask));
    base = __shfl(base, 0);
    if (m) {
      int off = __popcll(mask & ((1ull << lane) - 1ull));
      keys[base + off] = r;
    }
  }
  __syncthreads();
  int n = lcnt;
  for (int i = tid; i < n; i += 1024) {
    u64 ki = keys[i];
    int r = 0;
#pragma unroll 8
    for (int j = 0; j < n; ++j) r += (keys[j] > ki);
    if (r < CAP) {
      u32 v = 0xFFFFFFFFu - (u32)ki;
      etok[e * CAP + r] = (int)(v >> 3);
      ep[e * CAP + r]   = __uint_as_float((u32)(ki >> 32));
    }
  }
  if (tid == 0) ecnt[e] = n < CAP ? n : CAP;
}

// ---------------- gather kept tokens -> bf16 ----------------
__global__ __launch_bounds__(256) void gather_kernel(
    const float* __restrict__ x, const int* __restrict__ etok, const int* __restrict__ ecnt,
    __bf16* __restrict__ Xe) {
  int e = blockIdx.x >> 10;
  int r = blockIdx.x & 1023;
  __bf16* dst = Xe + ((size_t)(e * CAP + r)) * DM;
  int tid = threadIdx.x;
  bf4v o;
  if (r < ecnt[e]) {
    int tok = etok[e * CAP + r] >> 1;
    f4 v = reinterpret_cast<const f4*>(x + (size_t)tok * DM)[tid];
    o[0] = (__bf16)v[0]; o[1] = (__bf16)v[1]; o[2] = (__bf16)v[2]; o[3] = (__bf16)v[3];
  } else {
    o[0] = (__bf16)0.f; o[1] = (__bf16)0.f; o[2] = (__bf16)0.f; o[3] = (__bf16)0.f;
  }
  reinterpret_cast<bf4v*>(dst)[tid] = o;
}

// ---------------- weight conversion fp32 -> bf16, all three in one launch ----------------
__global__ __launch_bounds__(256) void convert_all(
    const float* __restrict__ wg, const float* __restrict__ wu, const float* __restrict__ wd,
    __bf16* __restrict__ wgb, __bf16* __restrict__ wub, __bf16* __restrict__ wdb) {
  int e = blockIdx.y;
  int z = blockIdx.z;
  int idx = blockIdx.x * 256 + threadIdx.x;
  bf8v o;
  if (z < 2) {
    const float* src = z ? wu : wg;
    __bf16* dst = z ? wub : wgb;
    int row = idx >> 7;
    int c = (idx & 127) << 3;
    if (row < HD) {
      const float* s = src + ((size_t)e * HD + row) * DM + c;
      f4 a = *reinterpret_cast<const f4*>(s);
      f4 b = *reinterpret_cast<const f4*>(s + 4);
#pragma unroll
      for (int q = 0; q < 4; ++q) { o[q] = (__bf16)a[q]; o[q + 4] = (__bf16)b[q]; }
    } else {
#pragma unroll
      for (int q = 0; q < 8; ++q) o[q] = (__bf16)0.f;
    }
    *reinterpret_cast<bf8v*>(dst + ((size_t)e * HP + row) * DM + c) = o;
  } else {
    int row = idx / 344;
    int c = (idx % 344) << 3;
    const float* s = wd + ((size_t)e * DM + row) * HD + c;
    if (c + 8 <= HD) {
      f2 q0 = *reinterpret_cast<const f2*>(s);
      f2 q1 = *reinterpret_cast<const f2*>(s + 2);
      f2 q2 = *reinterpret_cast<const f2*>(s + 4);
      f2 q3 = *reinterpret_cast<const f2*>(s + 6);
      o[0] = (__bf16)q0[0]; o[1] = (__bf16)q0[1]; o[2] = (__bf16)q1[0]; o[3] = (__bf16)q1[1];
      o[4] = (__bf16)q2[0]; o[5] = (__bf16)q2[1]; o[6] = (__bf16)q3[0]; o[7] = (__bf16)q3[1];
    } else {
#pragma unroll
      for (int q = 0; q < 8; ++q) o[q] = (c + q < HD) ? (__bf16)s[q] : (__bf16)0.f;
    }
    *reinterpret_cast<bf8v*>(wdb + ((size_t)e * DM + row) * HP + c) = o;
  }
}

// ============ bf16 GEMMs: 128x128 tiles, wave tile 64x64, gload_lds + XOR swizzle ============
// 2-barrier loop: STAGE(kt); barrier; COMPUTE(kt); barrier. Single-buffered LDS.

// GEMM1: H[e] = silu(Xe Wg^T) * (Xe Wu^T). 4 waves 2x2; each wave 64x64 of G AND U.
// N = 2752 = 21 full 128-tiles + overlapping tail tile at n0=2624 (idempotent dup writes).
__global__ __launch_bounds__(256) void gemm1_swiglu_bf(
    const __bf16* __restrict__ Xe, const __bf16* __restrict__ wgb, const __bf16* __restrict__ wub,
    const int* __restrict__ ecnt, __bf16* __restrict__ Hbuf) {
  int bid = blockIdx.x;                  // 1408 = 8 XCD * 176; expert e pinned to XCD e
  int e   = bid & 7;
  int rem = bid >> 3;                    // 0..175
  int pm  = rem & 7;
  int pn  = rem >> 3;                    // 0..21
  int ne = ecnt[e];
  int m0 = pm * 128;
  int n0 = (pn < 21) ? pn * 128 : (HP - 128);   // 2624 tail overlap
  if (m0 >= ne) return;

  __shared__ __align__(16) __bf16 As[128 * 64];    // 16 KB
  __shared__ __align__(16) __bf16 Bgs[128 * 64];   // 16 KB
  __shared__ __align__(16) __bf16 Bus[128 * 64];   // 16 KB

  int tid = threadIdx.x;
  int lane = tid & 63, wave = tid >> 6;
  int wm = wave >> 1, wn = wave & 1;
  int lr = lane >> 3;
  int scol = (((lane & 7) << 4) ^ (lr << 4)) >> 1;   // pre-swizzled src col (elems)

  f4 accG[4][4], accU[4][4];
#pragma unroll
  for (int m = 0; m < 4; ++m)
#pragma unroll
    for (int n = 0; n < 4; ++n) { accG[m][n] = (f4){0,0,0,0}; accU[m][n] = (f4){0,0,0,0}; }

  const __bf16* Ab = Xe + ((size_t)(e * CAP + m0)) * DM;
  const __bf16* Gb = wgb + (size_t)e * HP * DM + (size_t)n0 * DM;
  const __bf16* Ub = wub + (size_t)e * HP * DM + (size_t)n0 * DM;

  for (int kt = 0; kt < 16; ++kt) {
    int k0 = kt * 64;
#pragma unroll
    for (int i = 0; i < 4; ++i) {            // A: 128 rows
      int rb = i * 32 + wave * 8 + lr;
      gl_lds16(Ab + (size_t)rb * DM + k0 + scol, (char*)As + i * 4096 + wave * 1024);
    }
#pragma unroll
    for (int i = 0; i < 4; ++i) {            // Bg, Bu: 128 rows each
      int rb = i * 32 + wave * 8 + lr;
      gl_lds16(Gb + (size_t)rb * DM + k0 + scol, (char*)Bgs + i * 4096 + wave * 1024);
      gl_lds16(Ub + (size_t)rb * DM + k0 + scol, (char*)Bus + i * 4096 + wave * 1024);
    }
    __syncthreads();
#pragma unroll
    for (int kk = 0; kk < 2; ++kk) {
      int kb = kk * 64 + ((lane >> 4) << 4);
      bf8v af[4];
#pragma unroll
      for (int m = 0; m < 4; ++m) {
        int row = wm * 64 + m * 16 + (lane & 15);
        af[m] = *reinterpret_cast<const bf8v*>(
            reinterpret_cast<const char*>(As) + ((row * 128 + kb) ^ ((row & 7) << 4)));
      }
      bf8v bg[4], bu[4];
#pragma unroll
      for (int n = 0; n < 4; ++n) {
        int row = wn * 64 + n * 16 + (lane & 15);
        int off = (row * 128 + kb) ^ ((row & 7) << 4);
        bg[n] = *reinterpret_cast<const bf8v*>(reinterpret_cast<const char*>(Bgs) + off);
        bu[n] = *reinterpret_cast<const bf8v*>(reinterpret_cast<const char*>(Bus) + off);
      }
#pragma unroll
      for (int m = 0; m < 4; ++m)
#pragma unroll
        for (int n = 0; n < 4; ++n) {
          accG[m][n] = mfma_bf16(af[m], bg[n], accG[m][n]);
          accU[m][n] = mfma_bf16(af[m], bu[n], accU[m][n]);
        }
    }
    __syncthreads();
  }

  __bf16* hb = Hbuf + (size_t)e * CAP * HP;
#pragma unroll
  for (int m = 0; m < 4; ++m)
#pragma unroll
    for (int n = 0; n < 4; ++n)
#pragma unroll
      for (int j = 0; j < 4; ++j) {
        int row = m0 + wm * 64 + m * 16 + ((lane >> 4) << 2) + j;
        int col = n0 + wn * 64 + n * 16 + (lane & 15);
        float g = accG[m][n][j];
        float u = accU[m][n][j];
        float h = g / (1.f + expf(-g)) * u;
        hb[(size_t)row * HP + col] = (__bf16)h;
      }
}

// GEMM2: out[tok] += p * (H Wd^T). 128x128 tile, wave tile 64x64, K=2752.
__global__ __launch_bounds__(256) void gemm2_down_bf(
    const __bf16* __restrict__ Hbuf, const __bf16* __restrict__ wdb,
    const int* __restrict__ ecnt, const int* __restrict__ etok, const float* __restrict__ ep,
    float* __restrict__ out) {
  int bid = blockIdx.x;                  // 512 = 8 XCD * 64
  int e   = bid & 7;
  int rem = bid >> 3;                    // 0..63
  int pm  = rem & 7;
  int pn  = rem >> 3;                    // 0..7
  int ne = ecnt[e];
  int m0 = pm * 128, n0 = pn * 128;
  if (m0 >= ne) return;

  __shared__ __align__(16) __bf16 As[128 * 64];    // 16 KB
  __shared__ __align__(16) __bf16 Bs[128 * 64];    // 16 KB

  int tid = threadIdx.x;
  int lane = tid & 63, wave = tid >> 6;
  int wm = wave >> 1, wn = wave & 1;
  int lr = lane >> 3;
  int scol = (((lane & 7) << 4) ^ (lr << 4)) >> 1;

  f4 acc[4][4];
#pragma unroll
  for (int m = 0; m < 4; ++m)
#pragma unroll
    for (int n = 0; n < 4; ++n) acc[m][n] = (f4){0,0,0,0};

  const __bf16* Ab = Hbuf + (size_t)(e * CAP + m0) * HP;
  const __bf16* Bb = wdb + (size_t)e * DM * HP + (size_t)n0 * HP;

  for (int kt = 0; kt < HP / 64; ++kt) {       // 43 steps
    int k0 = kt * 64;
#pragma unroll
    for (int i = 0; i < 4; ++i) {
      int rb = i * 32 + wave * 8 + lr;
      gl_lds16(Ab + (size_t)rb * HP + k0 + scol, (char*)As + i * 4096 + wave * 1024);
    }
#pragma unroll
    for (int i = 0; i < 4; ++i) {
      int rb = i * 32 + wave * 8 + lr;
      gl_lds16(Bb + (size_t)rb * HP + k0 + scol, (char*)Bs + i * 4096 + wave * 1024);
    }
    __syncthreads();
#pragma unroll
    for (int kk = 0; kk < 2; ++kk) {
      int kb = kk * 64 + ((lane >> 4) << 4);
      bf8v af[4];
#pragma unroll
      for (int m = 0; m < 4; ++m) {
        int row = wm * 64 + m * 16 + (lane & 15);
        af[m] = *reinterpret_cast<const bf8v*>(
            reinterpret_cast<const char*>(As) + ((row * 128 + kb) ^ ((row & 7) << 4)));
      }
      bf8v bfr[4];
#pragma unroll
      for (int n = 0; n < 4; ++n) {
        int row = wn * 64 + n * 16 + (lane & 15);
        bfr[n] = *reinterpret_cast<const bf8v*>(
            reinterpret_cast<const char*>(Bs) + ((row * 128 + kb) ^ ((row & 7) << 4)));
      }
#pragma unroll
      for (int m = 0; m < 4; ++m)
#pragma unroll
        for (int n = 0; n < 4; ++n)
          acc[m][n] = mfma_bf16(af[m], bfr[n], acc[m][n]);
    }
    __syncthreads();
  }

#pragma unroll
  for (int m = 0; m < 4; ++m)
#pragma unroll
    for (int j = 0; j < 4; ++j) {
      int row = m0 + wm * 64 + m * 16 + ((lane >> 4) << 2) + j;
      if (row < ne) {
        float p  = ep[e * CAP + row];
        int tok  = etok[e * CAP + row] >> 1;
        float* orow = out + (size_t)tok * DM;
#pragma unroll
        for (int n = 0; n < 4; ++n) {
          int col = n0 + wn * 64 + n * 16 + (lane & 15);
          atomicAdd(orow + col, acc[m][n][j] * p);   // <=2 adds/elem, deterministic
        }
      }
    }
}

// ---------------- launch ----------------
extern "C" void kernel_launch(void* const* d_in, const int* in_sizes, int n_in,
                              void* d_out, int out_size, void* d_ws, size_t ws_size,
                              hipStream_t stream) {
  const float* x     = (const float*)d_in[0];
  const float* gw    = (const float*)d_in[1];
  const float* wgate = (const float*)d_in[2];
  const float* wup   = (const float*)d_in[3];
  const float* wdown = (const float*)d_in[4];
  float* out = (float*)d_out;
  char* ws = (char*)d_ws;

  u64*   recs = (u64*)  (ws + 0);           // 131072
  int*   etok = (int*)  (ws + 131072);      // 32768
  float* ep   = (float*)(ws + 163840);      // 32768
  int*   ecnt = (int*)  (ws + 196608);      // 256
  __bf16* Xe  = (__bf16*)(ws + 196864);     // 16777216 -> 16974080
  __bf16* Hbuf= (__bf16*)(ws + 16974080);   // 45088768 -> 62062848
  __bf16* wgb = (__bf16*)(ws + 62062848);   // 45088768 -> 107151616
  __bf16* wub = (__bf16*)(ws + 107151616);  // 45088768 -> 152240384
  __bf16* wdb = (__bf16*)(ws + 152240384);  // 45088768 -> 197329152

  hipMemsetAsync(out, 0, (size_t)NTOK * DM * sizeof(float), stream);
  router_kernel<<<NTOK / 16, 256, 0, stream>>>(x, gw, recs);
  rank_select<<<NE, 1024, 0, stream>>>(recs, etok, ep, ecnt);
  gather_kernel<<<NE * CAP, 256, 0, stream>>>(x, etok, ecnt, Xe);

  dim3 gcv(1376, NE, 3);
  convert_all<<<gcv, 256, 0, stream>>>(wgate, wup, wdown, wgb, wub, wdb);
  gemm1_swiglu_bf<<<8 * 176, 256, 0, stream>>>(Xe, wgb, wub, ecnt, Hbuf);
  gemm2_down_bf<<<8 * 64, 256, 0, stream>>>(Hbuf, wdb, ecnt, etok, ep, out);
}

// Round 7
// 427.794 us; speedup vs baseline: 1.1565x; 1.1183x over previous
//
#include <hip/hip_runtime.h>

// MoE: T=8192, D=1024, E=8, top-2, H=2730 (pad 2752), capacity=1024.
// Best-known composite (R7):
//   memset(out) -> router (atomic-free) -> rank_select -> gather(bf16)
//   -> convert_all (fp32->bf16, one launch) -> gemm1 (R4 config: 128Mx(64G+64U),
//   32KB LDS, 88 VGPR, 2-barrier) -> gemm2 (R6 config: 128x128, K=2752).
// Lesson log: R5 explicit dbuf -20% (occupancy loss); R6 128x128 dual-acc -30%
// (VGPR 156 > 128 cliff). Residency corner {<=128 VGPR, <=32KB LDS} dominates.

typedef float  f4  __attribute__((ext_vector_type(4)));
typedef float  f2  __attribute__((ext_vector_type(2)));
typedef __bf16 bf8v __attribute__((ext_vector_type(8)));
typedef __bf16 bf4v __attribute__((ext_vector_type(4)));
typedef unsigned int u32;
typedef unsigned long long u64;
typedef u32 u4v __attribute__((ext_vector_type(4)));

#define NTOK 8192
#define DM   1024
#define NE   8
#define HD   2730
#define HP   2752
#define CAP  1024

__device__ __forceinline__ f4 mfma_bf16(bf8v a, bf8v b, f4 c) {
  return __builtin_amdgcn_mfma_f32_16x16x32_bf16(a, b, c, 0, 0, 0);
}

__device__ __forceinline__ void gl_lds16(const void* g, void* l) {
  __builtin_amdgcn_global_load_lds(
      (const __attribute__((address_space(1))) unsigned int*)g,
      (__attribute__((address_space(3))) unsigned int*)l, 16, 0, 0);
}

// ---------------- router: logits + top-2 + softmax -> dense u64 records (no atomics) ----------------
// rec = (p_bits << 32) | (0xFFFFFFFF - (flat_pos*8 | expert)); u64 '>' == (p desc, pos asc).
__global__ __launch_bounds__(256) void router_kernel(
    const float* __restrict__ x, const float* __restrict__ gw, u64* __restrict__ recs) {
  __shared__ float gws[NE][DM];
  int tid = threadIdx.x;
  for (int i = tid * 4; i < NE * DM; i += 1024)
    *reinterpret_cast<f4*>(&gws[0][i]) = *reinterpret_cast<const f4*>(gw + i);
  __syncthreads();
  int lane = tid & 63, wave = tid >> 6;
  int tbase = blockIdx.x * 16 + wave * 4;
#pragma unroll
  for (int tt = 0; tt < 4; ++tt) {
    int t = tbase + tt;
    const f4* xr = reinterpret_cast<const f4*>(x + (size_t)t * DM);
    float acc[NE];
#pragma unroll
    for (int e = 0; e < NE; ++e) acc[e] = 0.f;
#pragma unroll
    for (int i = 0; i < 4; ++i) {
      f4 xv = xr[i * 64 + lane];
#pragma unroll
      for (int e = 0; e < NE; ++e) {
        f4 gv = *reinterpret_cast<const f4*>(&gws[e][i * 256 + lane * 4]);
        acc[e] += xv[0] * gv[0] + xv[1] * gv[1] + xv[2] * gv[2] + xv[3] * gv[3];
      }
    }
#pragma unroll
    for (int e = 0; e < NE; ++e) {
      float v = acc[e];
#pragma unroll
      for (int off = 32; off > 0; off >>= 1) v += __shfl_xor(v, off);
      acc[e] = v;
    }
    if (lane == 0) {
      float l0 = -1e30f, l1 = -1e30f; int i0 = 0, i1 = 0;
#pragma unroll
      for (int e = 0; e < NE; ++e) {
        float v = acc[e];
        if (v > l0)      { l1 = l0; i1 = i0; l0 = v; i0 = e; }
        else if (v > l1) { l1 = v; i1 = e; }
      }
      float e1 = expf(l1 - l0);
      float s  = 1.f + e1;
      float p0 = 1.f / s, p1 = e1 / s;
      float s2 = p0 + p1;
      p0 /= s2; p1 /= s2;
      u32 pf0 = 0xFFFFFFFFu - (((u32)(2 * t)     << 3) | (u32)i0);
      u32 pf1 = 0xFFFFFFFFu - (((u32)(2 * t + 1) << 3) | (u32)i1);
      recs[2 * t]     = ((u64)__float_as_uint(p0) << 32) | pf0;
      recs[2 * t + 1] = ((u64)__float_as_uint(p1) << 32) | pf1;
    }
  }
}

// ---------------- rank_select: per-expert append (wave-aggregated LDS atomic) + count-rank ----------------
__global__ __launch_bounds__(1024) void rank_select(
    const u64* __restrict__ recs, int* __restrict__ etok, float* __restrict__ ep,
    int* __restrict__ ecnt) {
  __shared__ u64 keys[8192];   // n <= 8192 structurally
  __shared__ int lcnt;
  int e = blockIdx.x;
  int tid = threadIdx.x;
  int lane = tid & 63;
  if (tid == 0) lcnt = 0;
  __syncthreads();
  for (int s = tid; s < 2 * NTOK; s += 1024) {
    u64 r = recs[s];
    bool m = ((0xFFFFFFFFu - (u32)r) & 7u) == (u32)e;
    u64 mask = __ballot(m);
    int base = 0;
    if (lane == 0 && mask) base = atomicAdd(&lcnt, __popcll(mask));
    base = __shfl(base, 0);
    if (m) {
      int off = __popcll(mask & ((1ull << lane) - 1ull));
      keys[base + off] = r;
    }
  }
  __syncthreads();
  int n = lcnt;
  for (int i = tid; i < n; i += 1024) {
    u64 ki = keys[i];
    int r = 0;
#pragma unroll 8
    for (int j = 0; j < n; ++j) r += (keys[j] > ki);
    if (r < CAP) {
      u32 v = 0xFFFFFFFFu - (u32)ki;
      etok[e * CAP + r] = (int)(v >> 3);
      ep[e * CAP + r]   = __uint_as_float((u32)(ki >> 32));
    }
  }
  if (tid == 0) ecnt[e] = n < CAP ? n : CAP;
}

// ---------------- gather kept tokens -> bf16 ----------------
__global__ __launch_bounds__(256) void gather_kernel(
    const float* __restrict__ x, const int* __restrict__ etok, const int* __restrict__ ecnt,
    __bf16* __restrict__ Xe) {
  int e = blockIdx.x >> 10;
  int r = blockIdx.x & 1023;
  __bf16* dst = Xe + ((size_t)(e * CAP + r)) * DM;
  int tid = threadIdx.x;
  bf4v o;
  if (r < ecnt[e]) {
    int tok = etok[e * CAP + r] >> 1;
    f4 v = reinterpret_cast<const f4*>(x + (size_t)tok * DM)[tid];
    o[0] = (__bf16)v[0]; o[1] = (__bf16)v[1]; o[2] = (__bf16)v[2]; o[3] = (__bf16)v[3];
  } else {
    o[0] = (__bf16)0.f; o[1] = (__bf16)0.f; o[2] = (__bf16)0.f; o[3] = (__bf16)0.f;
  }
  reinterpret_cast<bf4v*>(dst)[tid] = o;
}

// ---------------- weight conversion fp32 -> bf16, all three in one launch ----------------
__global__ __launch_bounds__(256) void convert_all(
    const float* __restrict__ wg, const float* __restrict__ wu, const float* __restrict__ wd,
    __bf16* __restrict__ wgb, __bf16* __restrict__ wub, __bf16* __restrict__ wdb) {
  int e = blockIdx.y;
  int z = blockIdx.z;
  int idx = blockIdx.x * 256 + threadIdx.x;
  bf8v o;
  if (z < 2) {
    const float* src = z ? wu : wg;
    __bf16* dst = z ? wub : wgb;
    int row = idx >> 7;
    int c = (idx & 127) << 3;
    if (row < HD) {
      const float* s = src + ((size_t)e * HD + row) * DM + c;
      f4 a = *reinterpret_cast<const f4*>(s);
      f4 b = *reinterpret_cast<const f4*>(s + 4);
#pragma unroll
      for (int q = 0; q < 4; ++q) { o[q] = (__bf16)a[q]; o[q + 4] = (__bf16)b[q]; }
    } else {
#pragma unroll
      for (int q = 0; q < 8; ++q) o[q] = (__bf16)0.f;
    }
    *reinterpret_cast<bf8v*>(dst + ((size_t)e * HP + row) * DM + c) = o;
  } else {
    int row = idx / 344;
    int c = (idx % 344) << 3;
    const float* s = wd + ((size_t)e * DM + row) * HD + c;
    if (c + 8 <= HD) {
      f2 q0 = *reinterpret_cast<const f2*>(s);
      f2 q1 = *reinterpret_cast<const f2*>(s + 2);
      f2 q2 = *reinterpret_cast<const f2*>(s + 4);
      f2 q3 = *reinterpret_cast<const f2*>(s + 6);
      o[0] = (__bf16)q0[0]; o[1] = (__bf16)q0[1]; o[2] = (__bf16)q1[0]; o[3] = (__bf16)q1[1];
      o[4] = (__bf16)q2[0]; o[5] = (__bf16)q2[1]; o[6] = (__bf16)q3[0]; o[7] = (__bf16)q3[1];
    } else {
#pragma unroll
      for (int q = 0; q < 8; ++q) o[q] = (c + q < HD) ? (__bf16)s[q] : (__bf16)0.f;
    }
    *reinterpret_cast<bf8v*>(wdb + ((size_t)e * DM + row) * HP + c) = o;
  }
}

// ============ GEMM1 (R4 config): tile 128Mx(64G+64U), wave 64x32 dual, 32KB LDS ============
// 2-barrier loop, gload_lds + both-sides XOR swizzle. 88 VGPR -> 4 blocks/CU resident.
__global__ __launch_bounds__(256) void gemm1_swiglu_bf(
    const __bf16* __restrict__ Xe, const __bf16* __restrict__ wgb, const __bf16* __restrict__ wub,
    const int* __restrict__ ecnt, __bf16* __restrict__ Hbuf) {
  int bid = blockIdx.x;                         // 2752 = 8 XCD * 344
  int wgid = (bid & 7) * 344 + (bid >> 3);      // each XCD owns one expert
  int pm = wgid & 7;
  int pn = (wgid >> 3) % 43;
  int e  = wgid / 344;
  int ne = ecnt[e];
  int m0 = pm * 128, n0 = pn * 64;
  if (m0 >= ne) return;

  __shared__ __align__(16) __bf16 As[128 * 64];    // 16 KB
  __shared__ __align__(16) __bf16 Bgs[64 * 64];    // 8 KB
  __shared__ __align__(16) __bf16 Bus[64 * 64];    // 8 KB

  int tid = threadIdx.x;
  int lane = tid & 63, wave = tid >> 6;
  int wm = wave >> 1, wn = wave & 1;
  int lr = lane >> 3;
  int scol = (((lane & 7) << 4) ^ (lr << 4)) >> 1;   // pre-swizzled src col (elems)

  f4 accG[4][2], accU[4][2];
#pragma unroll
  for (int m = 0; m < 4; ++m)
#pragma unroll
    for (int n = 0; n < 2; ++n) { accG[m][n] = (f4){0,0,0,0}; accU[m][n] = (f4){0,0,0,0}; }

  const __bf16* Ab = Xe + ((size_t)(e * CAP + m0)) * DM;
  const __bf16* Gb = wgb + (size_t)e * HP * DM + (size_t)n0 * DM;
  const __bf16* Ub = wub + (size_t)e * HP * DM + (size_t)n0 * DM;

  for (int kt = 0; kt < 16; ++kt) {
    int k0 = kt * 64;
#pragma unroll
    for (int i = 0; i < 4; ++i) {            // A: 128 rows
      int rb = i * 32 + wave * 8 + lr;
      gl_lds16(Ab + (size_t)rb * DM + k0 + scol, (char*)As + i * 4096 + wave * 1024);
    }
#pragma unroll
    for (int i = 0; i < 2; ++i) {            // Bg, Bu: 64 rows each
      int rb = i * 32 + wave * 8 + lr;
      gl_lds16(Gb + (size_t)rb * DM + k0 + scol, (char*)Bgs + i * 4096 + wave * 1024);
      gl_lds16(Ub + (size_t)rb * DM + k0 + scol, (char*)Bus + i * 4096 + wave * 1024);
    }
    __syncthreads();
#pragma unroll
    for (int kk = 0; kk < 2; ++kk) {
      int kb = kk * 64 + ((lane >> 4) << 4);
      bf8v af[4];
#pragma unroll
      for (int m = 0; m < 4; ++m) {
        int row = wm * 64 + m * 16 + (lane & 15);
        af[m] = *reinterpret_cast<const bf8v*>(
            reinterpret_cast<const char*>(As) + ((row * 128 + kb) ^ ((row & 7) << 4)));
      }
      bf8v bg[2], bu[2];
#pragma unroll
      for (int n = 0; n < 2; ++n) {
        int row = wn * 32 + n * 16 + (lane & 15);
        int off = (row * 128 + kb) ^ ((row & 7) << 4);
        bg[n] = *reinterpret_cast<const bf8v*>(reinterpret_cast<const char*>(Bgs) + off);
        bu[n] = *reinterpret_cast<const bf8v*>(reinterpret_cast<const char*>(Bus) + off);
      }
#pragma unroll
      for (int m = 0; m < 4; ++m)
#pragma unroll
        for (int n = 0; n < 2; ++n) {
          accG[m][n] = mfma_bf16(af[m], bg[n], accG[m][n]);
          accU[m][n] = mfma_bf16(af[m], bu[n], accU[m][n]);
        }
    }
    __syncthreads();
  }

  __bf16* hb = Hbuf + (size_t)e * CAP * HP;
#pragma unroll
  for (int m = 0; m < 4; ++m)
#pragma unroll
    for (int n = 0; n < 2; ++n)
#pragma unroll
      for (int j = 0; j < 4; ++j) {
        int row = m0 + wm * 64 + m * 16 + ((lane >> 4) << 2) + j;
        int col = n0 + wn * 32 + n * 16 + (lane & 15);
        float g = accG[m][n][j];
        float u = accU[m][n][j];
        float h = g / (1.f + expf(-g)) * u;
        hb[(size_t)row * HP + col] = (__bf16)h;
      }
}

// ============ GEMM2 (R6 config): 128x128 tile, wave 64x64, K=2752 ============
__global__ __launch_bounds__(256) void gemm2_down_bf(
    const __bf16* __restrict__ Hbuf, const __bf16* __restrict__ wdb,
    const int* __restrict__ ecnt, const int* __restrict__ etok, const float* __restrict__ ep,
    float* __restrict__ out) {
  int bid = blockIdx.x;                  // 512 = 8 XCD * 64
  int e   = bid & 7;
  int rem = bid >> 3;                    // 0..63
  int pm  = rem & 7;
  int pn  = rem >> 3;                    // 0..7
  int ne = ecnt[e];
  int m0 = pm * 128, n0 = pn * 128;
  if (m0 >= ne) return;

  __shared__ __align__(16) __bf16 As[128 * 64];    // 16 KB
  __shared__ __align__(16) __bf16 Bs[128 * 64];    // 16 KB

  int tid = threadIdx.x;
  int lane = tid & 63, wave = tid >> 6;
  int wm = wave >> 1, wn = wave & 1;
  int lr = lane >> 3;
  int scol = (((lane & 7) << 4) ^ (lr << 4)) >> 1;

  f4 acc[4][4];
#pragma unroll
  for (int m = 0; m < 4; ++m)
#pragma unroll
    for (int n = 0; n < 4; ++n) acc[m][n] = (f4){0,0,0,0};

  const __bf16* Ab = Hbuf + (size_t)(e * CAP + m0) * HP;
  const __bf16* Bb = wdb + (size_t)e * DM * HP + (size_t)n0 * HP;

  for (int kt = 0; kt < HP / 64; ++kt) {       // 43 steps
    int k0 = kt * 64;
#pragma unroll
    for (int i = 0; i < 4; ++i) {
      int rb = i * 32 + wave * 8 + lr;
      gl_lds16(Ab + (size_t)rb * HP + k0 + scol, (char*)As + i * 4096 + wave * 1024);
    }
#pragma unroll
    for (int i = 0; i < 4; ++i) {
      int rb = i * 32 + wave * 8 + lr;
      gl_lds16(Bb + (size_t)rb * HP + k0 + scol, (char*)Bs + i * 4096 + wave * 1024);
    }
    __syncthreads();
#pragma unroll
    for (int kk = 0; kk < 2; ++kk) {
      int kb = kk * 64 + ((lane >> 4) << 4);
      bf8v af[4];
#pragma unroll
      for (int m = 0; m < 4; ++m) {
        int row = wm * 64 + m * 16 + (lane & 15);
        af[m] = *reinterpret_cast<const bf8v*>(
            reinterpret_cast<const char*>(As) + ((row * 128 + kb) ^ ((row & 7) << 4)));
      }
      bf8v bfr[4];
#pragma unroll
      for (int n = 0; n < 4; ++n) {
        int row = wn * 64 + n * 16 + (lane & 15);
        bfr[n] = *reinterpret_cast<const bf8v*>(
            reinterpret_cast<const char*>(Bs) + ((row * 128 + kb) ^ ((row & 7) << 4)));
      }
#pragma unroll
      for (int m = 0; m < 4; ++m)
#pragma unroll
        for (int n = 0; n < 4; ++n)
          acc[m][n] = mfma_bf16(af[m], bfr[n], acc[m][n]);
    }
    __syncthreads();
  }

#pragma unroll
  for (int m = 0; m < 4; ++m)
#pragma unroll
    for (int j = 0; j < 4; ++j) {
      int row = m0 + wm * 64 + m * 16 + ((lane >> 4) << 2) + j;
      if (row < ne) {
        float p  = ep[e * CAP + row];
        int tok  = etok[e * CAP + row] >> 1;
        float* orow = out + (size_t)tok * DM;
#pragma unroll
        for (int n = 0; n < 4; ++n) {
          int col = n0 + wn * 64 + n * 16 + (lane & 15);
          atomicAdd(orow + col, acc[m][n][j] * p);   // <=2 adds/elem, deterministic
        }
      }
    }
}

// ---------------- launch ----------------
extern "C" void kernel_launch(void* const* d_in, const int* in_sizes, int n_in,
                              void* d_out, int out_size, void* d_ws, size_t ws_size,
                              hipStream_t stream) {
  const float* x     = (const float*)d_in[0];
  const float* gw    = (const float*)d_in[1];
  const float* wgate = (const float*)d_in[2];
  const float* wup   = (const float*)d_in[3];
  const float* wdown = (const float*)d_in[4];
  float* out = (float*)d_out;
  char* ws = (char*)d_ws;

  u64*   recs = (u64*)  (ws + 0);           // 131072
  int*   etok = (int*)  (ws + 131072);      // 32768
  float* ep   = (float*)(ws + 163840);      // 32768
  int*   ecnt = (int*)  (ws + 196608);      // 256
  __bf16* Xe  = (__bf16*)(ws + 196864);     // 16777216 -> 16974080
  __bf16* Hbuf= (__bf16*)(ws + 16974080);   // 45088768 -> 62062848
  __bf16* wgb = (__bf16*)(ws + 62062848);   // 45088768 -> 107151616
  __bf16* wub = (__bf16*)(ws + 107151616);  // 45088768 -> 152240384
  __bf16* wdb = (__bf16*)(ws + 152240384);  // 45088768 -> 197329152

  hipMemsetAsync(out, 0, (size_t)NTOK * DM * sizeof(float), stream);
  router_kernel<<<NTOK / 16, 256, 0, stream>>>(x, gw, recs);
  rank_select<<<NE, 1024, 0, stream>>>(recs, etok, ep, ecnt);
  gather_kernel<<<NE * CAP, 256, 0, stream>>>(x, etok, ecnt, Xe);

  dim3 gcv(1376, NE, 3);
  convert_all<<<gcv, 256, 0, stream>>>(wgate, wup, wdown, wgb, wub, wdb);
  gemm1_swiglu_bf<<<8 * 43 * 8, 256, 0, stream>>>(Xe, wgb, wub, ecnt, Hbuf);
  gemm2_down_bf<<<8 * 64, 256, 0, stream>>>(Hbuf, wdb, ecnt, etok, ep, out);
}

// Round 8
// 422.470 us; speedup vs baseline: 1.1711x; 1.0126x over previous
//
#include <hip/hip_runtime.h>

// MoE: T=8192, D=1024, E=8, top-2, H=2730 (pad 2752), capacity=1024.
// R8 pipeline (5 launches):
//   fused_prep (router + fp32->bf16 weight convert + out-zero, one launch)
//   -> rank_select -> gather(bf16) -> gemm1 (R4 config) -> gemm2 (R6 config).
// Lesson log: R5 explicit dbuf -20% (occupancy); R6 128x128 dual-acc -30%
// (VGPR 156 > 128 cliff). GEMMs stay in residency corner {<=128 VGPR, <=32KB LDS}.

typedef float  f4  __attribute__((ext_vector_type(4)));
typedef float  f2  __attribute__((ext_vector_type(2)));
typedef __bf16 bf8v __attribute__((ext_vector_type(8)));
typedef __bf16 bf4v __attribute__((ext_vector_type(4)));
typedef unsigned int u32;
typedef unsigned long long u64;
typedef u32 u4v __attribute__((ext_vector_type(4)));

#define NTOK 8192
#define DM   1024
#define NE   8
#define HD   2730
#define HP   2752
#define CAP  1024

// fused_prep grid layout
#define RB0   0        // router: 512 blocks (first: overlaps convert, no tail)
#define GU0   512      // wgate convert: 11008 blocks
#define GU1   11520    // wup convert:   11008 blocks
#define WD0   22528    // wdown convert: 11008 blocks
#define ZR0   33536    // out zero:      1024 blocks
#define NPREP 34560

__device__ __forceinline__ f4 mfma_bf16(bf8v a, bf8v b, f4 c) {
  return __builtin_amdgcn_mfma_f32_16x16x32_bf16(a, b, c, 0, 0, 0);
}

__device__ __forceinline__ void gl_lds16(const void* g, void* l) {
  __builtin_amdgcn_global_load_lds(
      (const __attribute__((address_space(1))) unsigned int*)g,
      (__attribute__((address_space(3))) unsigned int*)l, 16, 0, 0);
}

// ---------------- fused_prep: router + weight convert + out-zero ----------------
// rec = (p_bits << 32) | (0xFFFFFFFF - (flat_pos*8 | expert)); u64 '>' == (p desc, pos asc).
__global__ __launch_bounds__(256) void fused_prep(
    const float* __restrict__ x, const float* __restrict__ gw,
    const float* __restrict__ wg, const float* __restrict__ wu, const float* __restrict__ wd,
    u64* __restrict__ recs, __bf16* __restrict__ wgb, __bf16* __restrict__ wub,
    __bf16* __restrict__ wdb, float* __restrict__ out) {
  __shared__ float gws[NE][DM];
  int bid = blockIdx.x;
  int tid = threadIdx.x;

  if (bid < GU0) {
    // ---- router: 16 tokens per block ----
    for (int i = tid * 4; i < NE * DM; i += 1024)
      *reinterpret_cast<f4*>(&gws[0][i]) = *reinterpret_cast<const f4*>(gw + i);
    __syncthreads();
    int lane = tid & 63, wave = tid >> 6;
    int tbase = bid * 16 + wave * 4;
#pragma unroll
    for (int tt = 0; tt < 4; ++tt) {
      int t = tbase + tt;
      const f4* xr = reinterpret_cast<const f4*>(x + (size_t)t * DM);
      float acc[NE];
#pragma unroll
      for (int e = 0; e < NE; ++e) acc[e] = 0.f;
#pragma unroll
      for (int i = 0; i < 4; ++i) {
        f4 xv = xr[i * 64 + lane];
#pragma unroll
        for (int e = 0; e < NE; ++e) {
          f4 gv = *reinterpret_cast<const f4*>(&gws[e][i * 256 + lane * 4]);
          acc[e] += xv[0] * gv[0] + xv[1] * gv[1] + xv[2] * gv[2] + xv[3] * gv[3];
        }
      }
#pragma unroll
      for (int e = 0; e < NE; ++e) {
        float v = acc[e];
#pragma unroll
        for (int off = 32; off > 0; off >>= 1) v += __shfl_xor(v, off);
        acc[e] = v;
      }
      if (lane == 0) {
        float l0 = -1e30f, l1 = -1e30f; int i0 = 0, i1 = 0;
#pragma unroll
        for (int e = 0; e < NE; ++e) {
          float v = acc[e];
          if (v > l0)      { l1 = l0; i1 = i0; l0 = v; i0 = e; }
          else if (v > l1) { l1 = v; i1 = e; }
        }
        float e1 = expf(l1 - l0);     // keep libm expf: p feeds the rank ordering
        float s  = 1.f + e1;
        float p0 = 1.f / s, p1 = e1 / s;
        float s2 = p0 + p1;
        p0 /= s2; p1 /= s2;
        u32 pf0 = 0xFFFFFFFFu - (((u32)(2 * t)     << 3) | (u32)i0);
        u32 pf1 = 0xFFFFFFFFu - (((u32)(2 * t + 1) << 3) | (u32)i1);
        recs[2 * t]     = ((u64)__float_as_uint(p0) << 32) | pf0;
        recs[2 * t + 1] = ((u64)__float_as_uint(p1) << 32) | pf1;
      }
    }
  } else if (bid < WD0) {
    // ---- wgate / wup: [NE][HD][DM] f32 -> [NE][HP][DM] bf16, pad rows zeroed ----
    int u = (bid < GU1) ? (bid - GU0) : (bid - GU1);
    const float* src = (bid < GU1) ? wg : wu;
    __bf16* dst = (bid < GU1) ? wgb : wub;
    int e = u / 1376;
    int idx = (u % 1376) * 256 + tid;
    int row = idx >> 7;
    int c = (idx & 127) << 3;
    bf8v o;
    if (row < HD) {
      const float* s = src + ((size_t)e * HD + row) * DM + c;
      f4 a = *reinterpret_cast<const f4*>(s);
      f4 b = *reinterpret_cast<const f4*>(s + 4);
#pragma unroll
      for (int q = 0; q < 4; ++q) { o[q] = (__bf16)a[q]; o[q + 4] = (__bf16)b[q]; }
    } else {
#pragma unroll
      for (int q = 0; q < 8; ++q) o[q] = (__bf16)0.f;
    }
    *reinterpret_cast<bf8v*>(dst + ((size_t)e * HP + row) * DM + c) = o;
  } else if (bid < ZR0) {
    // ---- wdown: [NE][DM][HD] f32 -> [NE][DM][HP] bf16, pad cols zeroed ----
    int u = bid - WD0;
    int e = u / 1376;
    int idx = (u % 1376) * 256 + tid;
    int row = idx / 344;
    int c = (idx % 344) << 3;
    const float* s = wd + ((size_t)e * DM + row) * HD + c;
    bf8v o;
    if (c + 8 <= HD) {
      f2 q0 = *reinterpret_cast<const f2*>(s);
      f2 q1 = *reinterpret_cast<const f2*>(s + 2);
      f2 q2 = *reinterpret_cast<const f2*>(s + 4);
      f2 q3 = *reinterpret_cast<const f2*>(s + 6);
      o[0] = (__bf16)q0[0]; o[1] = (__bf16)q0[1]; o[2] = (__bf16)q1[0]; o[3] = (__bf16)q1[1];
      o[4] = (__bf16)q2[0]; o[5] = (__bf16)q2[1]; o[6] = (__bf16)q3[0]; o[7] = (__bf16)q3[1];
    } else {
#pragma unroll
      for (int q = 0; q < 8; ++q) o[q] = (c + q < HD) ? (__bf16)s[q] : (__bf16)0.f;
    }
    *reinterpret_cast<bf8v*>(wdb + ((size_t)e * DM + row) * HP + c) = o;
  } else {
    // ---- zero out[]: 1024 blocks x 2048 f4 ----
    int z = bid - ZR0;
    f4* o4 = reinterpret_cast<f4*>(out);
    f4 zv = (f4){0.f, 0.f, 0.f, 0.f};
#pragma unroll
    for (int i = 0; i < 8; ++i) o4[(size_t)z * 2048 + i * 256 + tid] = zv;
  }
}

// ---------------- rank_select: per-expert append (wave-aggregated LDS atomic) + count-rank ----------------
__global__ __launch_bounds__(1024) void rank_select(
    const u64* __restrict__ recs, int* __restrict__ etok, float* __restrict__ ep,
    int* __restrict__ ecnt) {
  __shared__ u64 keys[8192];   // n <= 8192 structurally
  __shared__ int lcnt;
  int e = blockIdx.x;
  int tid = threadIdx.x;
  int lane = tid & 63;
  if (tid == 0) lcnt = 0;
  __syncthreads();
  for (int s = tid; s < 2 * NTOK; s += 1024) {
    u64 r = recs[s];
    bool m = ((0xFFFFFFFFu - (u32)r) & 7u) == (u32)e;
    u64 mask = __ballot(m);
    int base = 0;
    if (lane == 0 && mask) base = atomicAdd(&lcnt, __popcll(mask));
    base = __shfl(base, 0);
    if (m) {
      int off = __popcll(mask & ((1ull << lane) - 1ull));
      keys[base + off] = r;
    }
  }
  __syncthreads();
  int n = lcnt;
  for (int i = tid; i < n; i += 1024) {
    u64 ki = keys[i];
    int r = 0;
#pragma unroll 8
    for (int j = 0; j < n; ++j) r += (keys[j] > ki);
    if (r < CAP) {
      u32 v = 0xFFFFFFFFu - (u32)ki;
      etok[e * CAP + r] = (int)(v >> 3);
      ep[e * CAP + r]   = __uint_as_float((u32)(ki >> 32));
    }
  }
  if (tid == 0) ecnt[e] = n < CAP ? n : CAP;
}

// ---------------- gather kept tokens -> bf16 ----------------
__global__ __launch_bounds__(256) void gather_kernel(
    const float* __restrict__ x, const int* __restrict__ etok, const int* __restrict__ ecnt,
    __bf16* __restrict__ Xe) {
  int e = blockIdx.x >> 10;
  int r = blockIdx.x & 1023;
  __bf16* dst = Xe + ((size_t)(e * CAP + r)) * DM;
  int tid = threadIdx.x;
  bf4v o;
  if (r < ecnt[e]) {
    int tok = etok[e * CAP + r] >> 1;
    f4 v = reinterpret_cast<const f4*>(x + (size_t)tok * DM)[tid];
    o[0] = (__bf16)v[0]; o[1] = (__bf16)v[1]; o[2] = (__bf16)v[2]; o[3] = (__bf16)v[3];
  } else {
    o[0] = (__bf16)0.f; o[1] = (__bf16)0.f; o[2] = (__bf16)0.f; o[3] = (__bf16)0.f;
  }
  reinterpret_cast<bf4v*>(dst)[tid] = o;
}

// ============ GEMM1 (R4 config): tile 128Mx(64G+64U), wave 64x32 dual, 32KB LDS ============
// 2-barrier loop, gload_lds + both-sides XOR swizzle. 88 VGPR -> ~5 blocks/CU resident.
__global__ __launch_bounds__(256) void gemm1_swiglu_bf(
    const __bf16* __restrict__ Xe, const __bf16* __restrict__ wgb, const __bf16* __restrict__ wub,
    const int* __restrict__ ecnt, __bf16* __restrict__ Hbuf) {
  int bid = blockIdx.x;                         // 2752 = 8 XCD * 344
  int wgid = (bid & 7) * 344 + (bid >> 3);      // each XCD owns one expert
  int pm = wgid & 7;
  int pn = (wgid >> 3) % 43;
  int e  = wgid / 344;
  int ne = ecnt[e];
  int m0 = pm * 128, n0 = pn * 64;
  if (m0 >= ne) return;

  __shared__ __align__(16) __bf16 As[128 * 64];    // 16 KB
  __shared__ __align__(16) __bf16 Bgs[64 * 64];    // 8 KB
  __shared__ __align__(16) __bf16 Bus[64 * 64];    // 8 KB

  int tid = threadIdx.x;
  int lane = tid & 63, wave = tid >> 6;
  int wm = wave >> 1, wn = wave & 1;
  int lr = lane >> 3;
  int scol = (((lane & 7) << 4) ^ (lr << 4)) >> 1;   // pre-swizzled src col (elems)

  f4 accG[4][2], accU[4][2];
#pragma unroll
  for (int m = 0; m < 4; ++m)
#pragma unroll
    for (int n = 0; n < 2; ++n) { accG[m][n] = (f4){0,0,0,0}; accU[m][n] = (f4){0,0,0,0}; }

  const __bf16* Ab = Xe + ((size_t)(e * CAP + m0)) * DM;
  const __bf16* Gb = wgb + (size_t)e * HP * DM + (size_t)n0 * DM;
  const __bf16* Ub = wub + (size_t)e * HP * DM + (size_t)n0 * DM;

  for (int kt = 0; kt < 16; ++kt) {
    int k0 = kt * 64;
#pragma unroll
    for (int i = 0; i < 4; ++i) {            // A: 128 rows
      int rb = i * 32 + wave * 8 + lr;
      gl_lds16(Ab + (size_t)rb * DM + k0 + scol, (char*)As + i * 4096 + wave * 1024);
    }
#pragma unroll
    for (int i = 0; i < 2; ++i) {            // Bg, Bu: 64 rows each
      int rb = i * 32 + wave * 8 + lr;
      gl_lds16(Gb + (size_t)rb * DM + k0 + scol, (char*)Bgs + i * 4096 + wave * 1024);
      gl_lds16(Ub + (size_t)rb * DM + k0 + scol, (char*)Bus + i * 4096 + wave * 1024);
    }
    __syncthreads();
#pragma unroll
    for (int kk = 0; kk < 2; ++kk) {
      int kb = kk * 64 + ((lane >> 4) << 4);
      bf8v af[4];
#pragma unroll
      for (int m = 0; m < 4; ++m) {
        int row = wm * 64 + m * 16 + (lane & 15);
        af[m] = *reinterpret_cast<const bf8v*>(
            reinterpret_cast<const char*>(As) + ((row * 128 + kb) ^ ((row & 7) << 4)));
      }
      bf8v bg[2], bu[2];
#pragma unroll
      for (int n = 0; n < 2; ++n) {
        int row = wn * 32 + n * 16 + (lane & 15);
        int off = (row * 128 + kb) ^ ((row & 7) << 4);
        bg[n] = *reinterpret_cast<const bf8v*>(reinterpret_cast<const char*>(Bgs) + off);
        bu[n] = *reinterpret_cast<const bf8v*>(reinterpret_cast<const char*>(Bus) + off);
      }
#pragma unroll
      for (int m = 0; m < 4; ++m)
#pragma unroll
        for (int n = 0; n < 2; ++n) {
          accG[m][n] = mfma_bf16(af[m], bg[n], accG[m][n]);
          accU[m][n] = mfma_bf16(af[m], bu[n], accU[m][n]);
        }
    }
    __syncthreads();
  }

  __bf16* hb = Hbuf + (size_t)e * CAP * HP;
#pragma unroll
  for (int m = 0; m < 4; ++m)
#pragma unroll
    for (int n = 0; n < 2; ++n)
#pragma unroll
      for (int j = 0; j < 4; ++j) {
        int row = m0 + wm * 64 + m * 16 + ((lane >> 4) << 2) + j;
        int col = n0 + wn * 32 + n * 16 + (lane & 15);
        float g = accG[m][n][j];
        float u = accU[m][n][j];
        float h = g / (1.f + __expf(-g)) * u;    // silu; tolerance has huge slack
        hb[(size_t)row * HP + col] = (__bf16)h;
      }
}

// ============ GEMM2 (R6 config): 128x128 tile, wave 64x64, K=2752 ============
__global__ __launch_bounds__(256) void gemm2_down_bf(
    const __bf16* __restrict__ Hbuf, const __bf16* __restrict__ wdb,
    const int* __restrict__ ecnt, const int* __restrict__ etok, const float* __restrict__ ep,
    float* __restrict__ out) {
  int bid = blockIdx.x;                  // 512 = 8 XCD * 64
  int e   = bid & 7;
  int rem = bid >> 3;                    // 0..63
  int pm  = rem & 7;
  int pn  = rem >> 3;                    // 0..7
  int ne = ecnt[e];
  int m0 = pm * 128, n0 = pn * 128;
  if (m0 >= ne) return;

  __shared__ __align__(16) __bf16 As[128 * 64];    // 16 KB
  __shared__ __align__(16) __bf16 Bs[128 * 64];    // 16 KB

  int tid = threadIdx.x;
  int lane = tid & 63, wave = tid >> 6;
  int wm = wave >> 1, wn = wave & 1;
  int lr = lane >> 3;
  int scol = (((lane & 7) << 4) ^ (lr << 4)) >> 1;

  f4 acc[4][4];
#pragma unroll
  for (int m = 0; m < 4; ++m)
#pragma unroll
    for (int n = 0; n < 4; ++n) acc[m][n] = (f4){0,0,0,0};

  const __bf16* Ab = Hbuf + (size_t)(e * CAP + m0) * HP;
  const __bf16* Bb = wdb + (size_t)e * DM * HP + (size_t)n0 * HP;

  for (int kt = 0; kt < HP / 64; ++kt) {       // 43 steps
    int k0 = kt * 64;
#pragma unroll
    for (int i = 0; i < 4; ++i) {
      int rb = i * 32 + wave * 8 + lr;
      gl_lds16(Ab + (size_t)rb * HP + k0 + scol, (char*)As + i * 4096 + wave * 1024);
    }
#pragma unroll
    for (int i = 0; i < 4; ++i) {
      int rb = i * 32 + wave * 8 + lr;
      gl_lds16(Bb + (size_t)rb * HP + k0 + scol, (char*)Bs + i * 4096 + wave * 1024);
    }
    __syncthreads();
#pragma unroll
    for (int kk = 0; kk < 2; ++kk) {
      int kb = kk * 64 + ((lane >> 4) << 4);
      bf8v af[4];
#pragma unroll
      for (int m = 0; m < 4; ++m) {
        int row = wm * 64 + m * 16 + (lane & 15);
        af[m] = *reinterpret_cast<const bf8v*>(
            reinterpret_cast<const char*>(As) + ((row * 128 + kb) ^ ((row & 7) << 4)));
      }
      bf8v bfr[4];
#pragma unroll
      for (int n = 0; n < 4; ++n) {
        int row = wn * 64 + n * 16 + (lane & 15);
        bfr[n] = *reinterpret_cast<const bf8v*>(
            reinterpret_cast<const char*>(Bs) + ((row * 128 + kb) ^ ((row & 7) << 4)));
      }
#pragma unroll
      for (int m = 0; m < 4; ++m)
#pragma unroll
        for (int n = 0; n < 4; ++n)
          acc[m][n] = mfma_bf16(af[m], bfr[n], acc[m][n]);
    }
    __syncthreads();
  }

#pragma unroll
  for (int m = 0; m < 4; ++m)
#pragma unroll
    for (int j = 0; j < 4; ++j) {
      int row = m0 + wm * 64 + m * 16 + ((lane >> 4) << 2) + j;
      if (row < ne) {
        float p  = ep[e * CAP + row];
        int tok  = etok[e * CAP + row] >> 1;
        float* orow = out + (size_t)tok * DM;
#pragma unroll
        for (int n = 0; n < 4; ++n) {
          int col = n0 + wn * 64 + n * 16 + (lane & 15);
          atomicAdd(orow + col, acc[m][n][j] * p);   // <=2 adds/elem, deterministic
        }
      }
    }
}

// ---------------- launch ----------------
extern "C" void kernel_launch(void* const* d_in, const int* in_sizes, int n_in,
                              void* d_out, int out_size, void* d_ws, size_t ws_size,
                              hipStream_t stream) {
  const float* x     = (const float*)d_in[0];
  const float* gw    = (const float*)d_in[1];
  const float* wgate = (const float*)d_in[2];
  const float* wup   = (const float*)d_in[3];
  const float* wdown = (const float*)d_in[4];
  float* out = (float*)d_out;
  char* ws = (char*)d_ws;

  u64*   recs = (u64*)  (ws + 0);           // 131072
  int*   etok = (int*)  (ws + 131072);      // 32768
  float* ep   = (float*)(ws + 163840);      // 32768
  int*   ecnt = (int*)  (ws + 196608);      // 256
  __bf16* Xe  = (__bf16*)(ws + 196864);     // 16777216 -> 16974080
  __bf16* Hbuf= (__bf16*)(ws + 16974080);   // 45088768 -> 62062848
  __bf16* wgb = (__bf16*)(ws + 62062848);   // 45088768 -> 107151616
  __bf16* wub = (__bf16*)(ws + 107151616);  // 45088768 -> 152240384
  __bf16* wdb = (__bf16*)(ws + 152240384);  // 45088768 -> 197329152

  fused_prep<<<NPREP, 256, 0, stream>>>(x, gw, wgate, wup, wdown,
                                        recs, wgb, wub, wdb, out);
  rank_select<<<NE, 1024, 0, stream>>>(recs, etok, ep, ecnt);
  gather_kernel<<<NE * CAP, 256, 0, stream>>>(x, etok, ecnt, Xe);
  gemm1_swiglu_bf<<<8 * 43 * 8, 256, 0, stream>>>(Xe, wgb, wub, ecnt, Hbuf);
  gemm2_down_bf<<<8 * 64, 256, 0, stream>>>(Hbuf, wdb, ecnt, etok, ep, out);
}

// Round 9
// 412.537 us; speedup vs baseline: 1.1993x; 1.0241x over previous
//
#include <hip/hip_runtime.h>

// MoE: T=8192, D=1024, E=8, top-2, H=2730 (pad 2752), capacity=1024.
// R9 pipeline (5 launches), packed by dependency DAG:
//   K1 fused_prep1: router || wgate/wup fp32->bf16 convert
//   K2 fused_prep2: rank_select || wdown convert || out-zero   (1024 thr)
//   K3 gather(bf16) -> K4 gemm1 (R4 config) -> K5 gemm2 (128x64 retile).
// Lessons: R5 dbuf -20% (occupancy); R6 128x128 dual-acc -30% (VGPR cliff);
// R9: gemm2 512-block grid was TLP-starved -> retile to gemm1's geometry.

typedef float  f4  __attribute__((ext_vector_type(4)));
typedef float  f2  __attribute__((ext_vector_type(2)));
typedef __bf16 bf8v __attribute__((ext_vector_type(8)));
typedef __bf16 bf4v __attribute__((ext_vector_type(4)));
typedef unsigned int u32;
typedef unsigned long long u64;
typedef u32 u4v __attribute__((ext_vector_type(4)));

#define NTOK 8192
#define DM   1024
#define NE   8
#define HD   2730
#define HP   2752
#define CAP  1024

__device__ __forceinline__ f4 mfma_bf16(bf8v a, bf8v b, f4 c) {
  return __builtin_amdgcn_mfma_f32_16x16x32_bf16(a, b, c, 0, 0, 0);
}

__device__ __forceinline__ void gl_lds16(const void* g, void* l) {
  __builtin_amdgcn_global_load_lds(
      (const __attribute__((address_space(1))) unsigned int*)g,
      (__attribute__((address_space(3))) unsigned int*)l, 16, 0, 0);
}

// ================= K1: router + wgate/wup convert =================
// grid: [0,512) router (16 tok/block); [512, 512+2*11008) gate/up convert.
// rec = (p_bits << 32) | (0xFFFFFFFF - (flat_pos*8 | expert)); u64 '>' == (p desc, pos asc).
#define K1_GU0 512
#define K1_GU1 (512 + 11008)
#define K1_N   (512 + 22016)
__global__ __launch_bounds__(256) void fused_prep1(
    const float* __restrict__ x, const float* __restrict__ gw,
    const float* __restrict__ wg, const float* __restrict__ wu,
    u64* __restrict__ recs, __bf16* __restrict__ wgb, __bf16* __restrict__ wub) {
  __shared__ float gws[NE][DM];
  int bid = blockIdx.x;
  int tid = threadIdx.x;

  if (bid < K1_GU0) {
    for (int i = tid * 4; i < NE * DM; i += 1024)
      *reinterpret_cast<f4*>(&gws[0][i]) = *reinterpret_cast<const f4*>(gw + i);
    __syncthreads();
    int lane = tid & 63, wave = tid >> 6;
    int tbase = bid * 16 + wave * 4;
#pragma unroll
    for (int tt = 0; tt < 4; ++tt) {
      int t = tbase + tt;
      const f4* xr = reinterpret_cast<const f4*>(x + (size_t)t * DM);
      float acc[NE];
#pragma unroll
      for (int e = 0; e < NE; ++e) acc[e] = 0.f;
#pragma unroll
      for (int i = 0; i < 4; ++i) {
        f4 xv = xr[i * 64 + lane];
#pragma unroll
        for (int e = 0; e < NE; ++e) {
          f4 gv = *reinterpret_cast<const f4*>(&gws[e][i * 256 + lane * 4]);
          acc[e] += xv[0] * gv[0] + xv[1] * gv[1] + xv[2] * gv[2] + xv[3] * gv[3];
        }
      }
#pragma unroll
      for (int e = 0; e < NE; ++e) {
        float v = acc[e];
#pragma unroll
        for (int off = 32; off > 0; off >>= 1) v += __shfl_xor(v, off);
        acc[e] = v;
      }
      if (lane == 0) {
        float l0 = -1e30f, l1 = -1e30f; int i0 = 0, i1 = 0;
#pragma unroll
        for (int e = 0; e < NE; ++e) {
          float v = acc[e];
          if (v > l0)      { l1 = l0; i1 = i0; l0 = v; i0 = e; }
          else if (v > l1) { l1 = v; i1 = e; }
        }
        float e1 = expf(l1 - l0);     // libm expf: p feeds the rank ordering
        float s  = 1.f + e1;
        float p0 = 1.f / s, p1 = e1 / s;
        float s2 = p0 + p1;
        p0 /= s2; p1 /= s2;
        u32 pf0 = 0xFFFFFFFFu - (((u32)(2 * t)     << 3) | (u32)i0);
        u32 pf1 = 0xFFFFFFFFu - (((u32)(2 * t + 1) << 3) | (u32)i1);
        recs[2 * t]     = ((u64)__float_as_uint(p0) << 32) | pf0;
        recs[2 * t + 1] = ((u64)__float_as_uint(p1) << 32) | pf1;
      }
    }
  } else {
    // gate/up: [NE][HD][DM] f32 -> [NE][HP][DM] bf16, pad rows zeroed
    int u = (bid < K1_GU1) ? (bid - K1_GU0) : (bid - K1_GU1);
    const float* src = (bid < K1_GU1) ? wg : wu;
    __bf16* dst = (bid < K1_GU1) ? wgb : wub;
    int e = u / 1376;
    int idx = (u % 1376) * 256 + tid;
    int row = idx >> 7;
    int c = (idx & 127) << 3;
    bf8v o;
    if (row < HD) {
      const float* s = src + ((size_t)e * HD + row) * DM + c;
      f4 a = *reinterpret_cast<const f4*>(s);
      f4 b = *reinterpret_cast<const f4*>(s + 4);
#pragma unroll
      for (int q = 0; q < 4; ++q) { o[q] = (__bf16)a[q]; o[q + 4] = (__bf16)b[q]; }
    } else {
#pragma unroll
      for (int q = 0; q < 8; ++q) o[q] = (__bf16)0.f;
    }
    *reinterpret_cast<bf8v*>(dst + ((size_t)e * HP + row) * DM + c) = o;
  }
}

// ================= K2: rank_select + wdown convert + out-zero (1024 thr) =================
// grid: [0,8) rank; [8, 8+2752) wdown convert; [2760, 3016) zero out.
#define K2_WD0 8
#define K2_ZR0 (8 + 2752)
#define K2_N   (8 + 2752 + 256)
__global__ __launch_bounds__(1024) void fused_prep2(
    const u64* __restrict__ recs, const float* __restrict__ wd,
    int* __restrict__ etok, float* __restrict__ ep, int* __restrict__ ecnt,
    __bf16* __restrict__ wdb, float* __restrict__ out) {
  __shared__ u64 keys[8192];
  __shared__ int lcnt;
  int bid = blockIdx.x;
  int tid = threadIdx.x;

  if (bid < K2_WD0) {
    // ---- per-expert capacity rank ----
    int e = bid;
    int lane = tid & 63;
    if (tid == 0) lcnt = 0;
    __syncthreads();
    for (int s = tid; s < 2 * NTOK; s += 1024) {
      u64 r = recs[s];
      bool m = ((0xFFFFFFFFu - (u32)r) & 7u) == (u32)e;
      u64 mask = __ballot(m);
      int base = 0;
      if (lane == 0 && mask) base = atomicAdd(&lcnt, __popcll(mask));
      base = __shfl(base, 0);
      if (m) {
        int off = __popcll(mask & ((1ull << lane) - 1ull));
        keys[base + off] = r;
      }
    }
    __syncthreads();
    int n = lcnt;
    for (int i = tid; i < n; i += 1024) {
      u64 ki = keys[i];
      int r = 0;
#pragma unroll 8
      for (int j = 0; j < n; ++j) r += (keys[j] > ki);
      if (r < CAP) {
        u32 v = 0xFFFFFFFFu - (u32)ki;
        etok[e * CAP + r] = (int)(v >> 3);
        ep[e * CAP + r]   = __uint_as_float((u32)(ki >> 32));
      }
    }
    if (tid == 0) ecnt[e] = n < CAP ? n : CAP;
  } else if (bid < K2_ZR0) {
    // ---- wdown: [NE][DM][HD] f32 -> [NE][DM][HP] bf16, pad cols zeroed ----
    int u = bid - K2_WD0;           // 0..2751; 344 blocks/expert
    int e = u / 344;
    int idx = (u % 344) * 1024 + tid;   // 0..352255 per expert
    int row = idx / 344;                 // HP/8 = 344 chunks per row
    int c = (idx % 344) << 3;
    const float* s = wd + ((size_t)e * DM + row) * HD + c;
    bf8v o;
    if (c + 8 <= HD) {
      f2 q0 = *reinterpret_cast<const f2*>(s);
      f2 q1 = *reinterpret_cast<const f2*>(s + 2);
      f2 q2 = *reinterpret_cast<const f2*>(s + 4);
      f2 q3 = *reinterpret_cast<const f2*>(s + 6);
      o[0] = (__bf16)q0[0]; o[1] = (__bf16)q0[1]; o[2] = (__bf16)q1[0]; o[3] = (__bf16)q1[1];
      o[4] = (__bf16)q2[0]; o[5] = (__bf16)q2[1]; o[6] = (__bf16)q3[0]; o[7] = (__bf16)q3[1];
    } else {
#pragma unroll
      for (int q = 0; q < 8; ++q) o[q] = (c + q < HD) ? (__bf16)s[q] : (__bf16)0.f;
    }
    *reinterpret_cast<bf8v*>(wdb + ((size_t)e * DM + row) * HP + c) = o;
  } else {
    // ---- zero out[]: 256 blocks x 1024 thr x 8 f4 ----
    int z = bid - K2_ZR0;
    f4* o4 = reinterpret_cast<f4*>(out);
    f4 zv = (f4){0.f, 0.f, 0.f, 0.f};
#pragma unroll
    for (int i = 0; i < 8; ++i) o4[(size_t)z * 8192 + i * 1024 + tid] = zv;
  }
}

// ---------------- gather kept tokens -> bf16 ----------------
__global__ __launch_bounds__(256) void gather_kernel(
    const float* __restrict__ x, const int* __restrict__ etok, const int* __restrict__ ecnt,
    __bf16* __restrict__ Xe) {
  int e = blockIdx.x >> 10;
  int r = blockIdx.x & 1023;
  __bf16* dst = Xe + ((size_t)(e * CAP + r)) * DM;
  int tid = threadIdx.x;
  bf4v o;
  if (r < ecnt[e]) {
    int tok = etok[e * CAP + r] >> 1;
    f4 v = reinterpret_cast<const f4*>(x + (size_t)tok * DM)[tid];
    o[0] = (__bf16)v[0]; o[1] = (__bf16)v[1]; o[2] = (__bf16)v[2]; o[3] = (__bf16)v[3];
  } else {
    o[0] = (__bf16)0.f; o[1] = (__bf16)0.f; o[2] = (__bf16)0.f; o[3] = (__bf16)0.f;
  }
  reinterpret_cast<bf4v*>(dst)[tid] = o;
}

// ============ GEMM1 (R4 config): tile 128Mx(64G+64U), wave 64x32 dual, 32KB LDS ============
__global__ __launch_bounds__(256) void gemm1_swiglu_bf(
    const __bf16* __restrict__ Xe, const __bf16* __restrict__ wgb, const __bf16* __restrict__ wub,
    const int* __restrict__ ecnt, __bf16* __restrict__ Hbuf) {
  int bid = blockIdx.x;                         // 2752 = 8 XCD * 344
  int wgid = (bid & 7) * 344 + (bid >> 3);      // each XCD owns one expert
  int pm = wgid & 7;
  int pn = (wgid >> 3) % 43;
  int e  = wgid / 344;
  int ne = ecnt[e];
  int m0 = pm * 128, n0 = pn * 64;
  if (m0 >= ne) return;

  __shared__ __align__(16) __bf16 As[128 * 64];    // 16 KB
  __shared__ __align__(16) __bf16 Bgs[64 * 64];    // 8 KB
  __shared__ __align__(16) __bf16 Bus[64 * 64];    // 8 KB

  int tid = threadIdx.x;
  int lane = tid & 63, wave = tid >> 6;
  int wm = wave >> 1, wn = wave & 1;
  int lr = lane >> 3;
  int scol = (((lane & 7) << 4) ^ (lr << 4)) >> 1;   // pre-swizzled src col (elems)

  f4 accG[4][2], accU[4][2];
#pragma unroll
  for (int m = 0; m < 4; ++m)
#pragma unroll
    for (int n = 0; n < 2; ++n) { accG[m][n] = (f4){0,0,0,0}; accU[m][n] = (f4){0,0,0,0}; }

  const __bf16* Ab = Xe + ((size_t)(e * CAP + m0)) * DM;
  const __bf16* Gb = wgb + (size_t)e * HP * DM + (size_t)n0 * DM;
  const __bf16* Ub = wub + (size_t)e * HP * DM + (size_t)n0 * DM;

  for (int kt = 0; kt < 16; ++kt) {
    int k0 = kt * 64;
#pragma unroll
    for (int i = 0; i < 4; ++i) {            // A: 128 rows
      int rb = i * 32 + wave * 8 + lr;
      gl_lds16(Ab + (size_t)rb * DM + k0 + scol, (char*)As + i * 4096 + wave * 1024);
    }
#pragma unroll
    for (int i = 0; i < 2; ++i) {            // Bg, Bu: 64 rows each
      int rb = i * 32 + wave * 8 + lr;
      gl_lds16(Gb + (size_t)rb * DM + k0 + scol, (char*)Bgs + i * 4096 + wave * 1024);
      gl_lds16(Ub + (size_t)rb * DM + k0 + scol, (char*)Bus + i * 4096 + wave * 1024);
    }
    __syncthreads();
#pragma unroll
    for (int kk = 0; kk < 2; ++kk) {
      int kb = kk * 64 + ((lane >> 4) << 4);
      bf8v af[4];
#pragma unroll
      for (int m = 0; m < 4; ++m) {
        int row = wm * 64 + m * 16 + (lane & 15);
        af[m] = *reinterpret_cast<const bf8v*>(
            reinterpret_cast<const char*>(As) + ((row * 128 + kb) ^ ((row & 7) << 4)));
      }
      bf8v bg[2], bu[2];
#pragma unroll
      for (int n = 0; n < 2; ++n) {
        int row = wn * 32 + n * 16 + (lane & 15);
        int off = (row * 128 + kb) ^ ((row & 7) << 4);
        bg[n] = *reinterpret_cast<const bf8v*>(reinterpret_cast<const char*>(Bgs) + off);
        bu[n] = *reinterpret_cast<const bf8v*>(reinterpret_cast<const char*>(Bus) + off);
      }
#pragma unroll
      for (int m = 0; m < 4; ++m)
#pragma unroll
        for (int n = 0; n < 2; ++n) {
          accG[m][n] = mfma_bf16(af[m], bg[n], accG[m][n]);
          accU[m][n] = mfma_bf16(af[m], bu[n], accU[m][n]);
        }
    }
    __syncthreads();
  }

  __bf16* hb = Hbuf + (size_t)e * CAP * HP;
#pragma unroll
  for (int m = 0; m < 4; ++m)
#pragma unroll
    for (int n = 0; n < 2; ++n)
#pragma unroll
      for (int j = 0; j < 4; ++j) {
        int row = m0 + wm * 64 + m * 16 + ((lane >> 4) << 2) + j;
        int col = n0 + wn * 32 + n * 16 + (lane & 15);
        float g = accG[m][n][j];
        float u = accU[m][n][j];
        float h = g / (1.f + __expf(-g)) * u;    // silu; tolerance has huge slack
        hb[(size_t)row * HP + col] = (__bf16)h;
      }
}

// ============ GEMM2 (retiled): tile 128x64, wave 64x32, 24KB LDS, 1024 blocks ============
__global__ __launch_bounds__(256) void gemm2_down_bf(
    const __bf16* __restrict__ Hbuf, const __bf16* __restrict__ wdb,
    const int* __restrict__ ecnt, const int* __restrict__ etok, const float* __restrict__ ep,
    float* __restrict__ out) {
  int bid = blockIdx.x;                  // 1024 = 8 XCD * 128
  int e   = bid & 7;                     // expert pinned to XCD
  int rem = bid >> 3;                    // 0..127
  int pm  = rem & 7;
  int pn  = rem >> 3;                    // 0..15
  int ne = ecnt[e];
  int m0 = pm * 128, n0 = pn * 64;
  if (m0 >= ne) return;

  __shared__ __align__(16) __bf16 As[128 * 64];    // 16 KB
  __shared__ __align__(16) __bf16 Bs[64 * 64];     // 8 KB

  int tid = threadIdx.x;
  int lane = tid & 63, wave = tid >> 6;
  int wm = wave >> 1, wn = wave & 1;
  int lr = lane >> 3;
  int scol = (((lane & 7) << 4) ^ (lr << 4)) >> 1;

  f4 acc[4][2];
#pragma unroll
  for (int m = 0; m < 4; ++m)
#pragma unroll
    for (int n = 0; n < 2; ++n) acc[m][n] = (f4){0,0,0,0};

  const __bf16* Ab = Hbuf + (size_t)(e * CAP + m0) * HP;
  const __bf16* Bb = wdb + (size_t)e * DM * HP + (size_t)n0 * HP;

  for (int kt = 0; kt < HP / 64; ++kt) {       // 43 steps
    int k0 = kt * 64;
#pragma unroll
    for (int i = 0; i < 4; ++i) {
      int rb = i * 32 + wave * 8 + lr;
      gl_lds16(Ab + (size_t)rb * HP + k0 + scol, (char*)As + i * 4096 + wave * 1024);
    }
#pragma unroll
    for (int i = 0; i < 2; ++i) {
      int rb = i * 32 + wave * 8 + lr;
      gl_lds16(Bb + (size_t)rb * HP + k0 + scol, (char*)Bs + i * 4096 + wave * 1024);
    }
    __syncthreads();
#pragma unroll
    for (int kk = 0; kk < 2; ++kk) {
      int kb = kk * 64 + ((lane >> 4) << 4);
      bf8v af[4];
#pragma unroll
      for (int m = 0; m < 4; ++m) {
        int row = wm * 64 + m * 16 + (lane & 15);
        af[m] = *reinterpret_cast<const bf8v*>(
            reinterpret_cast<const char*>(As) + ((row * 128 + kb) ^ ((row & 7) << 4)));
      }
      bf8v bfr[2];
#pragma unroll
      for (int n = 0; n < 2; ++n) {
        int row = wn * 32 + n * 16 + (lane & 15);
        bfr[n] = *reinterpret_cast<const bf8v*>(
            reinterpret_cast<const char*>(Bs) + ((row * 128 + kb) ^ ((row & 7) << 4)));
      }
#pragma unroll
      for (int m = 0; m < 4; ++m)
#pragma unroll
        for (int n = 0; n < 2; ++n)
          acc[m][n] = mfma_bf16(af[m], bfr[n], acc[m][n]);
    }
    __syncthreads();
  }

#pragma unroll
  for (int m = 0; m < 4; ++m)
#pragma unroll
    for (int j = 0; j < 4; ++j) {
      int row = m0 + wm * 64 + m * 16 + ((lane >> 4) << 2) + j;
      if (row < ne) {
        float p  = ep[e * CAP + row];
        int tok  = etok[e * CAP + row] >> 1;
        float* orow = out + (size_t)tok * DM;
#pragma unroll
        for (int n = 0; n < 2; ++n) {
          int col = n0 + wn * 32 + n * 16 + (lane & 15);
          atomicAdd(orow + col, acc[m][n][j] * p);   // <=2 adds/elem
        }
      }
    }
}

// ---------------- launch ----------------
extern "C" void kernel_launch(void* const* d_in, const int* in_sizes, int n_in,
                              void* d_out, int out_size, void* d_ws, size_t ws_size,
                              hipStream_t stream) {
  const float* x     = (const float*)d_in[0];
  const float* gw    = (const float*)d_in[1];
  const float* wgate = (const float*)d_in[2];
  const float* wup   = (const float*)d_in[3];
  const float* wdown = (const float*)d_in[4];
  float* out = (float*)d_out;
  char* ws = (char*)d_ws;

  u64*   recs = (u64*)  (ws + 0);           // 131072
  int*   etok = (int*)  (ws + 131072);      // 32768
  float* ep   = (float*)(ws + 163840);      // 32768
  int*   ecnt = (int*)  (ws + 196608);      // 256
  __bf16* Xe  = (__bf16*)(ws + 196864);     // 16777216 -> 16974080
  __bf16* Hbuf= (__bf16*)(ws + 16974080);   // 45088768 -> 62062848
  __bf16* wgb = (__bf16*)(ws + 62062848);   // 45088768 -> 107151616
  __bf16* wub = (__bf16*)(ws + 107151616);  // 45088768 -> 152240384
  __bf16* wdb = (__bf16*)(ws + 152240384);  // 45088768 -> 197329152

  fused_prep1<<<K1_N, 256, 0, stream>>>(x, gw, wgate, wup, recs, wgb, wub);
  fused_prep2<<<K2_N, 1024, 0, stream>>>(recs, wdown, etok, ep, ecnt, wdb, out);
  gather_kernel<<<NE * CAP, 256, 0, stream>>>(x, etok, ecnt, Xe);
  gemm1_swiglu_bf<<<8 * 43 * 8, 256, 0, stream>>>(Xe, wgb, wub, ecnt, Hbuf);
  gemm2_down_bf<<<8 * 128, 256, 0, stream>>>(Hbuf, wdb, ecnt, etok, ep, out);
}